// Round 10
// baseline (304.205 us; speedup 1.0000x reference)
//
#include <hip/hip_runtime.h>

#define B_   16
#define NH   12
#define SEQ  1024
#define CD   768
#define HD_  64
#define MTOT (B_ * SEQ)
// 1/sqrt(64) * log2(e): QK^T scores land in log2 domain for exp2
#define QSCALE 0.18033688f

typedef __attribute__((ext_vector_type(4)))  float  f32x4;
typedef __attribute__((ext_vector_type(16))) float  f32x16;
typedef __attribute__((ext_vector_type(8)))  __bf16 bf16x8;
typedef __attribute__((ext_vector_type(2)))  unsigned u32x2;

#define WAITV4  asm volatile("s_waitcnt vmcnt(4)" ::: "memory")
#define WAITV0  asm volatile("s_waitcnt vmcnt(0)" ::: "memory")
#define LGKM0   asm volatile("s_waitcnt lgkmcnt(0)" ::: "memory")
#define BAR     __builtin_amdgcn_s_barrier()
#define SB0     __builtin_amdgcn_sched_barrier(0)

__device__ __forceinline__ unsigned short f2bf(float f) {
  unsigned u = __float_as_uint(f);
  u = (u + 0x7FFFu + ((u >> 16) & 1u)) >> 16;  // RNE
  return (unsigned short)u;
}

__device__ __forceinline__ void gload16(const void* g, void* l) {
  __builtin_amdgcn_global_load_lds(
      (const __attribute__((address_space(1))) void*)g,
      (__attribute__((address_space(3))) void*)l, 16, 0, 0);
}

__device__ __forceinline__ u32x2 pswap(unsigned x, unsigned y) {
  return __builtin_amdgcn_permlane32_swap(x, y, false, false);
}

// ---- merged prep: x f32->bf16 + both weight transpose-converts ----------

__global__ __launch_bounds__(256)
void prep_kernel(const float* __restrict__ x,
                 const float* __restrict__ Wqkv,
                 const float* __restrict__ Wproj,
                 unsigned short* __restrict__ xb,
                 unsigned short* __restrict__ wqT,
                 unsigned short* __restrict__ wpT) {
  __shared__ float tile[32][33];
  const int bid = blockIdx.x;
  const int tid = threadIdx.x;
  if (bid < 12288) {
    const int i = bid * 256 + tid;                 // n4 = 3145728 exact
    float4 f = reinterpret_cast<const float4*>(x)[i];
    uint2 o;
    o.x = (unsigned)f2bf(f.x) | ((unsigned)f2bf(f.y) << 16);
    o.y = (unsigned)f2bf(f.z) | ((unsigned)f2bf(f.w) << 16);
    reinterpret_cast<uint2*>(xb)[i] = o;
  } else {
    const float* W;
    unsigned short* Wt;
    int N, b2;
    if (bid < 12288 + 1728) { b2 = bid - 12288; W = Wqkv; Wt = wqT; N = 2304; }
    else                    { b2 = bid - 14016; W = Wproj; Wt = wpT; N = 768; }
    const int nb = N / 32;
    const int j0 = (b2 % nb) * 32, k0 = (b2 / nb) * 32;
    const int tx = tid & 31, ty = tid >> 5;
    #pragma unroll
    for (int i = 0; i < 4; i++)
      tile[ty + 8 * i][tx] = W[(size_t)(k0 + ty + 8 * i) * N + j0 + tx];
    __syncthreads();
    #pragma unroll
    for (int i = 0; i < 4; i++)
      Wt[(size_t)(j0 + ty + 8 * i) * 768 + k0 + tx] = f2bf(tile[tx][ty + 8 * i]);
  }
}

// ---- LDS fragment load: 128B rows, XOR swizzle (row&7)<<4 ---------------

__device__ __forceinline__ bf16x8 lds128(const unsigned short* buf, int row, int cb) {
  int byte = (row << 7) + (cb ^ ((row & 7) << 4));
  return *reinterpret_cast<const bf16x8*>((const char*)buf + byte);
}

// ---- GEMM 256x256, BK=64, 8 waves, 4-phase fine-interleaved pipeline ----
// C = A[M][768] * Bt[N][768]^T, 12 K-tiles, 2-tile LDS double buffer.
// Tile t data in buf t&1: A-halves staged at t-2 p2/p3, B-halves at t-1 p0/p1;
// all guaranteed present by the vmcnt(4)+BAR at t-1 phase-3 end.
// Phase = {ds_read quadrant frags | stage 1 half-tile | BAR | lgkm0 | 16 MFMA | BAR}.

#define READ_AF(FRH)                                                          \
  _Pragma("unroll") for (int kk = 0; kk < 2; kk++)                            \
  _Pragma("unroll") for (int i = 0; i < 4; i++)                               \
    af[kk][i] = lds128(Ac, wm * 128 + (FRH) * 64 + i * 16 + rl, kk * 64 + fcb);
#define READ_BF(FNH)                                                          \
  _Pragma("unroll") for (int kk = 0; kk < 2; kk++)                            \
  _Pragma("unroll") for (int j = 0; j < 2; j++)                               \
    bf[kk][(FNH) * 2 + j] =                                                   \
        lds128(Bc, wn * 64 + (FNH) * 32 + j * 16 + rl, kk * 64 + fcb);
#define MFMA16(FRH, FNH)                                                      \
  __builtin_amdgcn_s_setprio(1);                                              \
  _Pragma("unroll") for (int kk = 0; kk < 2; kk++)                            \
  _Pragma("unroll") for (int i = 0; i < 4; i++)                               \
  _Pragma("unroll") for (int j = 0; j < 2; j++)                               \
    acc[(FRH) * 4 + i][(FNH) * 2 + j] = __builtin_amdgcn_mfma_f32_16x16x32_bf16( \
        af[kk][i], bf[kk][(FNH) * 2 + j], acc[(FRH) * 4 + i][(FNH) * 2 + j],  \
        0, 0, 0);                                                             \
  __builtin_amdgcn_s_setprio(0);

template <int MODE>
__global__ __launch_bounds__(512, 2)
void gemm256_kernel(const unsigned short* __restrict__ A,
                    const unsigned short* __restrict__ Bt,
                    unsigned short* __restrict__ qkvOut,
                    unsigned short* __restrict__ vtOut,
                    float* __restrict__ outF,
                    const float* __restrict__ bias) {
  __shared__ unsigned short lds[65536];            // 128 KiB
  // buf c bytes: A @ c*65536 (256 rows x 128B), B @ c*65536+32768

  const int tid = threadIdx.x;
  const int lane = tid & 63;
  const int wave = tid >> 6;
  const int wm = wave >> 2;                        // A rows wm*128
  const int wn = wave & 3;                         // B rows wn*64
  const int m0 = blockIdx.x << 8;
  const int j0 = blockIdx.y << 8;
  const int rl = lane & 15;
  const int fcb = (lane >> 4) << 4;

  const int srow = tid >> 3;                       // 0..63
  const int sc16 = (tid & 7) << 4;
  const int scs = sc16 ^ ((srow & 7) << 4);        // pre-swizzled source col

  const char* const aRow = (const char*)A  + ((size_t)(m0 + srow) * 768) * 2 + scs;
  const char* const bRow = (const char*)Bt + ((size_t)(j0 + srow) * 768) * 2 + scs;
  char* const dRowA = (char*)lds + srow * 128 + sc16;

  f32x4 acc[8][4] = {};

  auto stageA = [&](int kt, int h, int bb) {
    const char* src = aRow + (size_t)h * 196608 + kt * 128;
    char* dst = dRowA + bb * 65536 + h * 16384;
    gload16(src, dst);
    gload16(src + 98304, dst + 8192);
  };
  auto stageB = [&](int kt, int h, int bb) {
    const char* src = bRow + (size_t)h * 196608 + kt * 128;
    char* dst = dRowA + 32768 + bb * 65536 + h * 16384;
    gload16(src, dst);
    gload16(src + 98304, dst + 8192);
  };

  // prologue: t0 all 4 halves -> buf0; t1 A-halves -> buf1 (12 loads, age-ordered)
  stageA(0, 0, 0); stageA(0, 1, 0);
  stageB(0, 0, 0); stageB(0, 1, 0);
  stageA(1, 0, 1); stageA(1, 1, 1);
  WAITV4; BAR; SB0;

  bf16x8 af[2][4], bf[2][4];

  #pragma unroll 1
  for (int t = 0; t < 12; ++t) {
    const unsigned short* Ac = lds + (t & 1) * 32768;
    const unsigned short* Bc = Ac + 16384;
    const int n = (t & 1) ^ 1;
    // ---- p0: quadrant (fr0-3, fn0-1) ----
    READ_AF(0); READ_BF(0);
    if (t <= 10) stageB(t + 1, 0, n);
    BAR; LGKM0; SB0;
    MFMA16(0, 0);
    BAR;
    // ---- p1: (fr0-3, fn2-3) ----
    READ_BF(1);
    if (t <= 10) stageB(t + 1, 1, n);
    BAR; LGKM0; SB0;
    MFMA16(0, 1);
    BAR;
    // ---- p2: (fr4-7, fn2-3); stage overwrites Ah0 (readers done past p1 BAR) ----
    READ_AF(1);
    if (t <= 9) stageA(t + 2, 0, t & 1);
    BAR; LGKM0; SB0;
    MFMA16(1, 1);
    BAR;
    // ---- p3: (fr4-7, fn0-1); stage overwrites Ah1 (readers done past p2 BAR) ----
    if (t <= 9) stageA(t + 2, 1, t & 1);
    BAR; SB0;
    MFMA16(1, 0);
    if (t <= 9) { WAITV4; }          // leaves t+2's A-halves (4 loads) in flight
    else if (t == 10) { WAITV0; }    // tail drain: t11's 4 halves
    BAR; SB0;
  }

  const int g4 = (lane >> 4) << 2;

  if (MODE == 0) {
    const bool secV = (j0 >= 1536);
    const float scale = (j0 < 768) ? QSCALE : 1.0f;
    char* const ct = (char*)lds;
    if (!secV) {
      // Q/K: two m-half passes, m-major ctile [128][528B], coalesced 512B rows
      #pragma unroll
      for (int p = 0; p < 2; p++) {
        BAR;
        if (wm == p) {
          #pragma unroll
          for (int fr = 0; fr < 8; fr++)
            #pragma unroll
            for (int fn = 0; fn < 4; fn++) {
              const int j_l = wn * 64 + fn * 16 + rl;
              const int mrow = fr * 16 + g4;
              #pragma unroll
              for (int r = 0; r < 4; r++)
                *reinterpret_cast<unsigned short*>(ct + (mrow + r) * 528 + j_l * 2) =
                    f2bf(acc[fr][fn][r] * scale);
            }
        }
        LGKM0; BAR;
        const int c = tid & 31, r0 = tid >> 5;
        char* const gb = (char*)qkvOut + (size_t)(m0 + p * 128) * 4608 + j0 * 2 + c * 16;
        #pragma unroll
        for (int k = 0; k < 8; k++) {
          const int row = r0 + 16 * k;
          const uint4 d = *reinterpret_cast<const uint4*>(ct + row * 528 + c * 16);
          *reinterpret_cast<uint4*>(gb + (size_t)row * 4608) = d;
        }
      }
    } else {
      // V: two m-half passes, j-major ctile [256][264B] -> blocked Vt
      const int bidx = m0 >> 10;
      const int h0 = (j0 - 1536) >> 6;
      #pragma unroll
      for (int p = 0; p < 2; p++) {
        BAR;
        if (wm == p) {
          #pragma unroll
          for (int fr = 0; fr < 8; fr++)
            #pragma unroll
            for (int fn = 0; fn < 4; fn++) {
              const int j_l = wn * 64 + fn * 16 + rl;
              const int mrow = fr * 16 + g4;
              uint2 pkd;
              pkd.x = (unsigned)f2bf(acc[fr][fn][0]) |
                      ((unsigned)f2bf(acc[fr][fn][1]) << 16);
              pkd.y = (unsigned)f2bf(acc[fr][fn][2]) |
                      ((unsigned)f2bf(acc[fr][fn][3]) << 16);
              *reinterpret_cast<uint2*>(ct + j_l * 264 + mrow * 2) = pkd;
            }
        }
        LGKM0; BAR;
        const int c = tid & 15, r0 = tid >> 4;
        const int nblk = ((m0 & 1023) >> 7) + p;
        #pragma unroll
        for (int k = 0; k < 8; k++) {
          const int jr = r0 + 32 * k;
          const int h = h0 + (jr >> 6);
          const int d = jr & 63;
          const size_t dst = (((size_t)(bidx * NH + h) * 8 + nblk) * 64 + d) * 256 + c * 16;
          const uint4 v = *reinterpret_cast<const uint4*>(ct + jr * 264 + c * 16);
          *reinterpret_cast<uint4*>((char*)vtOut + dst) = v;
        }
      }
    }
  } else {
    // MODE 1: f32 + bias, 4 passes of 64 m-rows through ctile [64][260 f32]
    float* const ctf = (float*)lds;
    const int c = tid & 63, r0 = tid >> 6;
    float4 bv4 = *reinterpret_cast<const float4*>(bias + j0 + c * 4);
    #pragma unroll
    for (int p = 0; p < 4; p++) {
      BAR;
      if (wm == (p >> 1)) {
        #pragma unroll
        for (int i = 0; i < 4; i++) {
          const int fr = (p & 1) * 4 + i;
          #pragma unroll
          for (int fn = 0; fn < 4; fn++) {
            const int col = wn * 64 + fn * 16 + rl;
            #pragma unroll
            for (int r = 0; r < 4; r++)
              ctf[(i * 16 + g4 + r) * 260 + col] = acc[fr][fn][r];
          }
        }
      }
      LGKM0; BAR;
      #pragma unroll
      for (int k = 0; k < 8; k++) {
        const int row = r0 + 8 * k;
        f32x4 v = *reinterpret_cast<const f32x4*>(&ctf[row * 260 + c * 4]);
        v[0] += bv4.x; v[1] += bv4.y; v[2] += bv4.z; v[3] += bv4.w;
        *reinterpret_cast<f32x4*>(outF + (size_t)(m0 + p * 64 + row) * CD + j0 + c * 4) = v;
      }
    }
  }
}

// ---- flash attention: 32x32 swapped QK^T, in-lane softmax, permlane PV --
// block = (b*h, 128 q rows), 4 waves x 32 q rows each, KVBLK=64 dbuf
// Q/K read from qkv [B,N,2304] (Q pre-scaled); V from blocked Vt.

__global__ __launch_bounds__(256, 4)
void attn_kernel(const unsigned short* __restrict__ qkvB,  // [B][N][2304]
                 const unsigned short* __restrict__ Vt,    // [bh][8][64][128]
                 unsigned short* __restrict__ Og) {        // [B][1024][768] bf16
  __shared__ unsigned short ldsbuf[16384];
  __shared__ float sStat[2][4][32];  // [0]=corr, [1]=lsum

  unsigned short* const K0 = ldsbuf;
  unsigned short* const V0 = ldsbuf + 4096;
  unsigned short* const K1 = ldsbuf + 8192;
  unsigned short* const V1 = ldsbuf + 12288;
  unsigned short* const Qs = ldsbuf + 8192;  // 16KB, prologue only

  const int tid = threadIdx.x;
  const int lane = tid & 63;
  const int wave = tid >> 6;
  const int half = lane >> 5;
  const int q_l = lane & 31;
  const int bh = blockIdx.x;
  const int q0 = blockIdx.y * 128;
  const int b = bh / NH, head = bh - b * NH;

  const int sr = tid >> 3;                       // staging row 0..31
  const int scs = ((tid & 7) << 4) ^ ((sr & 7) << 4);

  const char* const xb_ = (const char*)qkvB + (size_t)b * 1024 * 4608;
  const int qoff = head * 128;                   // byte offset within row
  const int koff = qoff + 1536;
  const char* const vb0 = (const char*)Vt + (size_t)bh * 131072;

  // prologue: Q (128 rows) + KV tile 0
  {
    #pragma unroll
    for (int i = 0; i < 4; i++)
      gload16(xb_ + (size_t)(q0 + sr + 32 * i) * 4608 + qoff + scs,
              (char*)Qs + (tid + 256 * i) * 16);
    gload16(xb_ + (size_t)sr * 4608 + koff + scs, (char*)K0 + tid * 16);
    gload16(xb_ + (size_t)(sr + 32) * 4608 + koff + scs, (char*)K0 + 4096 + tid * 16);
    gload16(vb0 + sr * 256 + scs, (char*)V0 + tid * 16);
    gload16(vb0 + (sr + 32) * 256 + scs, (char*)V0 + 4096 + tid * 16);
  }
  __syncthreads();

  bf16x8 qf[4];
  #pragma unroll
  for (int c = 0; c < 4; c++)
    qf[c] = lds128(Qs, wave * 32 + q_l, 32 * c + 16 * half);
  __syncthreads();  // all waves done with Qs before buf1 prefetch overwrites it

  f32x16 o0 = {}, o1 = {};
  float mrun = -1e30f, lrun = 0.f;

  for (int t = 0; t < 16; t++) {
    const unsigned short* const Kc = (t & 1) ? K1 : K0;
    const unsigned short* const Vc = (t & 1) ? V1 : V0;
    unsigned short* const Kn = (t & 1) ? K0 : K1;
    unsigned short* const Vn = (t & 1) ? V0 : V1;
    if (t < 15) {
      const int kv1 = (t + 1) * 64;
      const char* const vtile = vb0 + (kv1 >> 7) * 16384 + ((kv1 >> 6) & 1) * 128;
      gload16(xb_ + (size_t)(kv1 + sr) * 4608 + koff + scs, (char*)Kn + tid * 16);
      gload16(xb_ + (size_t)(kv1 + sr + 32) * 4608 + koff + scs,
              (char*)Kn + 4096 + tid * 16);
      gload16(vtile + sr * 256 + scs, (char*)Vn + tid * 16);
      gload16(vtile + (sr + 32) * 256 + scs, (char*)Vn + 4096 + tid * 16);
    }

    // swapped QK^T: S^T tiles; lane pair (l, l+32) holds q-row l&31's 64 scores
    f32x16 s0 = {}, s1 = {};
    #pragma unroll
    for (int c = 0; c < 4; c++) {
      bf16x8 kf0 = lds128(Kc, q_l, 32 * c + 16 * half);
      bf16x8 kf1 = lds128(Kc, 32 + q_l, 32 * c + 16 * half);
      s0 = __builtin_amdgcn_mfma_f32_32x32x16_bf16(kf0, qf[c], s0, 0, 0, 0);
      s1 = __builtin_amdgcn_mfma_f32_32x32x16_bf16(kf1, qf[c], s1, 0, 0, 0);
    }

    // row max: 31 in-lane + 1 permlane pair-combine
    float vmax = fmaxf(s0[0], s1[0]);
    #pragma unroll
    for (int r = 1; r < 16; r++) vmax = fmaxf(vmax, fmaxf(s0[r], s1[r]));
    {
      u32x2 mx = pswap(__float_as_uint(vmax), __float_as_uint(vmax));
      vmax = fmaxf(__uint_as_float(mx[0]), __uint_as_float(mx[1]));
    }

    // defer-max (T13): rescale only when some row grew past THR=8 (log2 units)
    if (!__all(vmax <= mrun + 8.0f)) {
      const float mnew = fmaxf(mrun, vmax);
      const float corr = __builtin_amdgcn_exp2f(mrun - mnew);
      mrun = mnew;
      lrun *= corr;
      if (lane < 32) sStat[0][wave][q_l] = corr;
      f32x4 c4[4];
      #pragma unroll
      for (int j = 0; j < 4; j++)
        c4[j] = *reinterpret_cast<const f32x4*>(&sStat[0][wave][4 * half + 8 * j]);
      #pragma unroll
      for (int r = 0; r < 16; r++) {
        const float cc = c4[r >> 2][r & 3];
        o0[r] *= cc;
        o1[r] *= cc;
      }
    }

    // P = exp2(S - m), row-sum
    float tsum = 0.f;
    #pragma unroll
    for (int r = 0; r < 16; r++) {
      const float p0 = __builtin_amdgcn_exp2f(s0[r] - mrun);
      const float p1 = __builtin_amdgcn_exp2f(s1[r] - mrun);
      s0[r] = p0; s1[r] = p1;
      tsum += p0 + p1;
    }
    {
      u32x2 ts = pswap(__float_as_uint(tsum), __float_as_uint(tsum));
      tsum = __uint_as_float(ts[0]) + __uint_as_float(ts[1]);
    }
    lrun += tsum;

    // pack P to bf16 pair-words
    unsigned pk[2][8];
    #pragma unroll
    for (int w = 0; w < 8; w++) {
      asm("v_cvt_pk_bf16_f32 %0, %1, %2"
          : "=v"(pk[0][w]) : "v"(s0[2 * w]), "v"(s0[2 * w + 1]));
      asm("v_cvt_pk_bf16_f32 %0, %1, %2"
          : "=v"(pk[1][w]) : "v"(s1[2 * w]), "v"(s1[2 * w + 1]));
    }

    // PV: per kv-chunk c, 2 permlane swaps build the A-fragment (T12)
    #pragma unroll
    for (int c = 0; c < 4; c++) {
      const int st = c >> 1, cc = c & 1;
      u32x2 rA = pswap(pk[st][4 * cc + 0], pk[st][4 * cc + 2]);
      u32x2 rB = pswap(pk[st][4 * cc + 1], pk[st][4 * cc + 3]);
      union { unsigned u[4]; bf16x8 v; } pa;
      pa.u[0] = rA[0]; pa.u[1] = rB[0]; pa.u[2] = rA[1]; pa.u[3] = rB[1];
      bf16x8 vf0 = lds128(Vc, q_l, 32 * c + 16 * half);
      bf16x8 vf1 = lds128(Vc, 32 + q_l, 32 * c + 16 * half);
      o0 = __builtin_amdgcn_mfma_f32_32x32x16_bf16(pa.v, vf0, o0, 0, 0, 0);
      o1 = __builtin_amdgcn_mfma_f32_32x32x16_bf16(pa.v, vf1, o1, 0, 0, 0);
    }
    __syncthreads();
  }

  // epilogue: 1/l per O-reg q via per-wave stat buffer (broadcast reads)
  if (lane < 32) sStat[1][wave][q_l] = lrun;
  f32x4 rl4[4];
  #pragma unroll
  for (int j = 0; j < 4; j++) {
    f32x4 lv = *reinterpret_cast<const f32x4*>(&sStat[1][wave][4 * half + 8 * j]);
    #pragma unroll
    for (int e = 0; e < 4; e++) rl4[j][e] = __builtin_amdgcn_rcpf(lv[e]);
  }
  #pragma unroll
  for (int r = 0; r < 16; r++) {
    const int qq = q0 + wave * 32 + (r & 3) + 8 * (r >> 2) + 4 * half;
    const float rl = rl4[r >> 2][r & 3];
    const size_t base = ((size_t)b * SEQ + qq) * CD + head * HD_;
    Og[base + q_l]      = f2bf(o0[r] * rl);
    Og[base + 32 + q_l] = f2bf(o1[r] * rl);
  }
}

// ---- launch -------------------------------------------------------------

extern "C" void kernel_launch(void* const* d_in, const int* in_sizes, int n_in,
                              void* d_out, int out_size, void* d_ws, size_t ws_size,
                              hipStream_t stream) {
  const float* x     = (const float*)d_in[0];
  const float* Wqkv  = (const float*)d_in[1];
  const float* Wproj = (const float*)d_in[2];
  const float* bproj = (const float*)d_in[3];

  char* ws = (char*)d_ws;
  unsigned short* qkvB = (unsigned short*)(ws + 0);          // 75,497,472
  unsigned short* Vt   = (unsigned short*)(ws + 75497472);   // 25,165,824
  unsigned short* xb   = (unsigned short*)(ws + 100663296);  // 25,165,824
  unsigned short* ao   = (unsigned short*)(ws + 100663296);  // aliases xb (xb dead)
  unsigned short* wqT  = (unsigned short*)(ws + 125829120);  //  3,538,944
  unsigned short* wpT  = (unsigned short*)(ws + 129368064);  //  1,179,648
  if (ws_size < 130547712ull) return;

  prep_kernel<<<14592, 256, 0, stream>>>(x, Wqkv, Wproj, xb, wqT, wpT);
  gemm256_kernel<0><<<dim3(64, 9), 512, 0, stream>>>(xb, wqT, qkvB, Vt,
                                                     nullptr, nullptr);
  attn_kernel<<<dim3(B_ * NH, SEQ / 128), 256, 0, stream>>>(qkvB, Vt, ao);
  gemm256_kernel<1><<<dim3(64, 3), 512, 0, stream>>>(ao, wpT, nullptr, nullptr,
                                                     (float*)d_out, bproj);
}

// Round 11
// 189.771 us; speedup vs baseline: 1.6030x; 1.6030x over previous
//
#include <hip/hip_runtime.h>

#define B_   16
#define NH   12
#define SEQ  1024
#define CD   768
#define HD_  64
#define MTOT (B_ * SEQ)
// 1/sqrt(64) * log2(e): QK^T scores land in log2 domain for exp2
#define QSCALE 0.18033688f

typedef __attribute__((ext_vector_type(4)))  float  f32x4;
typedef __attribute__((ext_vector_type(16))) float  f32x16;
typedef __attribute__((ext_vector_type(8)))  __bf16 bf16x8;
typedef __attribute__((ext_vector_type(2)))  unsigned u32x2;

#define WAITV12 asm volatile("s_waitcnt vmcnt(12)" ::: "memory")
#define WAITV8  asm volatile("s_waitcnt vmcnt(8)" ::: "memory")
#define WAITV6  asm volatile("s_waitcnt vmcnt(6)" ::: "memory")
#define WAITV4  asm volatile("s_waitcnt vmcnt(4)" ::: "memory")
#define WAITV0  asm volatile("s_waitcnt vmcnt(0)" ::: "memory")
#define LGKM0   asm volatile("s_waitcnt lgkmcnt(0)" ::: "memory")
#define BAR     __builtin_amdgcn_s_barrier()
#define SB0     __builtin_amdgcn_sched_barrier(0)

__device__ __forceinline__ unsigned short f2bf(float f) {
  unsigned u = __float_as_uint(f);
  u = (u + 0x7FFFu + ((u >> 16) & 1u)) >> 16;  // RNE
  return (unsigned short)u;
}

__device__ __forceinline__ void gload16(const void* g, void* l) {
  __builtin_amdgcn_global_load_lds(
      (const __attribute__((address_space(1))) void*)g,
      (__attribute__((address_space(3))) void*)l, 16, 0, 0);
}

__device__ __forceinline__ u32x2 pswap(unsigned x, unsigned y) {
  return __builtin_amdgcn_permlane32_swap(x, y, false, false);
}

// ---- merged prep: x f32->bf16 + both weight transpose-converts ----------

__global__ __launch_bounds__(256)
void prep_kernel(const float* __restrict__ x,
                 const float* __restrict__ Wqkv,
                 const float* __restrict__ Wproj,
                 unsigned short* __restrict__ xb,
                 unsigned short* __restrict__ wqT,
                 unsigned short* __restrict__ wpT) {
  __shared__ float tile[32][33];
  const int bid = blockIdx.x;
  const int tid = threadIdx.x;
  if (bid < 12288) {
    const int i = bid * 256 + tid;                 // n4 = 3145728 exact
    float4 f = reinterpret_cast<const float4*>(x)[i];
    uint2 o;
    o.x = (unsigned)f2bf(f.x) | ((unsigned)f2bf(f.y) << 16);
    o.y = (unsigned)f2bf(f.z) | ((unsigned)f2bf(f.w) << 16);
    reinterpret_cast<uint2*>(xb)[i] = o;
  } else {
    const float* W;
    unsigned short* Wt;
    int N, b2;
    if (bid < 12288 + 1728) { b2 = bid - 12288; W = Wqkv; Wt = wqT; N = 2304; }
    else                    { b2 = bid - 14016; W = Wproj; Wt = wpT; N = 768; }
    const int nb = N / 32;
    const int j0 = (b2 % nb) * 32, k0 = (b2 / nb) * 32;
    const int tx = tid & 31, ty = tid >> 5;
    #pragma unroll
    for (int i = 0; i < 4; i++)
      tile[ty + 8 * i][tx] = W[(size_t)(k0 + ty + 8 * i) * N + j0 + tx];
    __syncthreads();
    #pragma unroll
    for (int i = 0; i < 4; i++)
      Wt[(size_t)(j0 + ty + 8 * i) * 768 + k0 + tx] = f2bf(tile[tx][ty + 8 * i]);
  }
}

// ---- LDS fragment loads -------------------------------------------------

// 64B rows, swizzle ((row>>1)&3)<<4  (GEMM staging buffers)
__device__ __forceinline__ bf16x8 ldsA64(const unsigned short* buf, int row, int g) {
  int byte = (row << 6) + ((g << 4) ^ (((row >> 1) & 3) << 4));
  return *reinterpret_cast<const bf16x8*>((const char*)buf + byte);
}
// 128B rows, swizzle (row&7)<<4  (attention tiles)
__device__ __forceinline__ bf16x8 lds128(const unsigned short* buf, int row, int cb) {
  int byte = (row << 7) + (cb ^ ((row & 7) << 4));
  return *reinterpret_cast<const bf16x8*>((const char*)buf + byte);
}

// ---- QKV GEMM: 128m x 256n tile, 4 waves (each owns 128x64), ring-3 -----
// qkv[M][2304] bf16 (Q pre-scaled) + V^T blocked Vt[bh][8][64][128].

__global__ __launch_bounds__(256, 2)
void gemm_qkv_kernel(const unsigned short* __restrict__ A,    // xb [16384][768]
                     const unsigned short* __restrict__ Bt,   // wqT [2304][768]
                     unsigned short* __restrict__ qkvOut,     // [16384][2304]
                     unsigned short* __restrict__ vtOut) {    // [192][8][64][128]
  constexpr int K = 768;
  // 72KB: A slots 3x8KB at u16 {0,4096,8192}; B slots 3x16KB at {12288,20480,28672}
  __shared__ unsigned short sbuf[36864];

  const int tid = threadIdx.x;
  const int lane = tid & 63;
  const int wave = tid >> 6;                      // wn: n-cols [wave*64, +64)
  const int m0 = blockIdx.x << 7;
  const int j0 = blockIdx.y << 8;                 // 256-wide panel (section-aligned)

  const int sr = tid >> 2;                        // staging row 0..63
  const int sc = (tid & 3) << 4;
  const int scs = sc ^ (((sr >> 1) & 3) << 4);    // pre-swizzled source col

  f32x4 acc[8][4] = {};

  const char* const aSrc = (const char*)(A  + (size_t)(m0 + sr) * K) + scs;
  const char* const bSrc = (const char*)(Bt + (size_t)(j0 + sr) * K) + scs;

  auto stageT = [&](int kt, int slot) {
    const int kb = kt * 64;                       // 32 u16 along K
    char* ad = (char*)sbuf + slot * 8192 + tid * 16;
    char* bd = (char*)sbuf + 24576 + slot * 16384 + tid * 16;
    gload16(aSrc + kb, ad);                       // A rows sr, sr+64
    gload16(aSrc + kb + 98304, ad + 4096);
    #pragma unroll
    for (int p = 0; p < 4; p++)                   // B rows sr+64p
      gload16(bSrc + kb + p * 98304, bd + p * 4096);
  };

  const int g = lane >> 4;
  const int rl = lane & 15;

  auto computeT = [&](int slot) {
    const unsigned short* As = sbuf + slot * 4096;
    const unsigned short* Bs = sbuf + 12288 + slot * 8192;
    bf16x8 bf[4], af[8];
    #pragma unroll
    for (int fn = 0; fn < 4; fn++) bf[fn] = ldsA64(Bs, wave * 64 + fn * 16 + rl, g);
    #pragma unroll
    for (int fr = 0; fr < 8; fr++) af[fr] = ldsA64(As, fr * 16 + rl, g);
    #pragma unroll
    for (int fr = 0; fr < 8; fr++)
      #pragma unroll
      for (int fn = 0; fn < 4; fn++)
        acc[fr][fn] = __builtin_amdgcn_mfma_f32_16x16x32_bf16(af[fr], bf[fn],
                                                              acc[fr][fn], 0, 0, 0);
  };

  // prologue: 3 slots in flight (18 loads/thread)
  stageT(0, 0);
  stageT(1, 1);
  stageT(2, 2);

  #pragma unroll 1
  for (int t = 0; t < 21; t += 3) {
    WAITV12; BAR; SB0;
    computeT(0);
    SB0; LGKM0; BAR;
    stageT(t + 3, 0);

    WAITV12; BAR; SB0;
    computeT(1);
    SB0; LGKM0; BAR;
    stageT(t + 4, 1);

    WAITV12; BAR; SB0;
    computeT(2);
    SB0; LGKM0; BAR;
    stageT(t + 5, 2);
  }
  // tail: K-steps 21,22,23
  WAITV12; BAR; SB0;
  computeT(0);
  WAITV6; BAR; SB0;
  computeT(1);
  WAITV0; BAR; SB0;
  computeT(2);

  // ---- LDS-coalesced epilogue ----
  const int g4 = g << 2;
  BAR;                                            // all waves done with slots
  const bool secV = (j0 >= 1536);
  const float scale = (j0 < 768) ? QSCALE : 1.0f;
  char* const ct = (char*)sbuf;
  if (!secV) {
    // m-major ctile: 128 rows x 528B (256 j + 16B pad)
    #pragma unroll
    for (int fr = 0; fr < 8; fr++)
      #pragma unroll
      for (int fn = 0; fn < 4; fn++) {
        const int j_l = wave * 64 + fn * 16 + rl;
        const int mb = fr * 16 + g4;
        #pragma unroll
        for (int r = 0; r < 4; r++)
          *reinterpret_cast<unsigned short*>(ct + (mb + r) * 528 + j_l * 2) =
              f2bf(acc[fr][fn][r] * scale);
      }
  } else {
    // j-major ctile: 256 rows x 264B (128 m + 8B pad), packed 8B writes
    #pragma unroll
    for (int fr = 0; fr < 8; fr++)
      #pragma unroll
      for (int fn = 0; fn < 4; fn++) {
        const int j_l = wave * 64 + fn * 16 + rl;
        const int mb = fr * 16 + g4;
        uint2 pkd;
        pkd.x = (unsigned)f2bf(acc[fr][fn][0]) | ((unsigned)f2bf(acc[fr][fn][1]) << 16);
        pkd.y = (unsigned)f2bf(acc[fr][fn][2]) | ((unsigned)f2bf(acc[fr][fn][3]) << 16);
        *reinterpret_cast<uint2*>(ct + j_l * 264 + mb * 2) = pkd;
      }
  }
  LGKM0; BAR;
  if (!secV) {
    const int c = tid & 31, r0 = tid >> 5;        // 32 x 16B chunks per row
    char* const gb = (char*)qkvOut + (size_t)m0 * 4608 + j0 * 2 + c * 16;
    #pragma unroll
    for (int k = 0; k < 16; k++) {
      const int row = r0 + 8 * k;
      const uint4 d = *reinterpret_cast<const uint4*>(ct + row * 528 + c * 16);
      *reinterpret_cast<uint4*>(gb + (size_t)row * 4608) = d;
    }
  } else {
    const int c = tid & 15, r0 = tid >> 4;        // 16 x 16B chunks per row
    const int bidx = m0 >> 10;
    const int nblk = (m0 & 1023) >> 7;
    #pragma unroll
    for (int k = 0; k < 16; k++) {
      const int jr = r0 + 16 * k;
      const int h = ((j0 - 1536) >> 6) + (jr >> 6);
      const int d = jr & 63;
      const size_t dst = ((size_t)((bidx * NH + h) * 8 + nblk) * 64 + d) * 256 + c * 16;
      const uint4 v = *reinterpret_cast<const uint4*>(ct + jr * 264 + c * 16);
      *reinterpret_cast<uint4*>((char*)vtOut + dst) = v;
    }
  }
}

// ---- proj GEMM: 128x128 depth-3 ring, direct f32 + bias epilogue --------

template <int MODE>
__global__ __launch_bounds__(256, 3)
void gemm128_kernel(const unsigned short* __restrict__ A,
                    const unsigned short* __restrict__ Bt,
                    float* __restrict__ outF,
                    const float* __restrict__ bias) {
  constexpr int K = 768;
  __shared__ unsigned short sbuf[24576];  // 48KB = 3 x (A 8KB + B 8KB)
  unsigned short* const A0 = sbuf;
  unsigned short* const Bb0 = sbuf + 4096;
  unsigned short* const A1 = sbuf + 8192;
  unsigned short* const Bb1 = sbuf + 12288;
  unsigned short* const A2 = sbuf + 16384;
  unsigned short* const Bb2 = sbuf + 20480;

  const int tid = threadIdx.x;
  const int lane = tid & 63;
  const int wave = tid >> 6;
  const int wm = (wave >> 1) << 6;
  const int wn = (wave & 1) << 6;
  const int m0 = blockIdx.x << 7;
  const int j0 = blockIdx.y << 7;

  const int sr = tid >> 2;
  const int sc = (tid & 3) << 4;
  const int scs = sc ^ (((sr >> 1) & 3) << 4);

  f32x4 acc[4][4] = {};

  const char* const ab  = (const char*)(A  + (size_t)(m0 + sr) * K) + scs;
  const char* const ab2 = (const char*)(A  + (size_t)(m0 + sr + 64) * K) + scs;
  const char* const bb  = (const char*)(Bt + (size_t)(j0 + sr) * K) + scs;
  const char* const bb2 = (const char*)(Bt + (size_t)(j0 + sr + 64) * K) + scs;

  auto stageT = [&](int kt, unsigned short* Ad, unsigned short* Bd) {
    const int kb = kt * 64;
    gload16(ab  + kb, (char*)Ad + tid * 16);
    gload16(ab2 + kb, (char*)Ad + 4096 + tid * 16);
    gload16(bb  + kb, (char*)Bd + tid * 16);
    gload16(bb2 + kb, (char*)Bd + 4096 + tid * 16);
  };

  auto computeT = [&](const unsigned short* As, const unsigned short* Bs) {
    bf16x8 af[4], bf[4];
    const int g = lane >> 4;
    #pragma unroll
    for (int fr = 0; fr < 4; fr++) af[fr] = ldsA64(As, wm + fr * 16 + (lane & 15), g);
    #pragma unroll
    for (int fn = 0; fn < 4; fn++) bf[fn] = ldsA64(Bs, wn + fn * 16 + (lane & 15), g);
    #pragma unroll
    for (int fr = 0; fr < 4; fr++)
      #pragma unroll
      for (int fn = 0; fn < 4; fn++)
        acc[fr][fn] = __builtin_amdgcn_mfma_f32_16x16x32_bf16(af[fr], bf[fn],
                                                              acc[fr][fn], 0, 0, 0);
  };

  stageT(0, A0, Bb0);
  stageT(1, A1, Bb1);
  stageT(2, A2, Bb2);

  #pragma unroll 1
  for (int t = 0; t < 21; t += 3) {
    WAITV8; BAR; SB0;
    computeT(A0, Bb0);
    SB0; LGKM0; BAR;
    stageT(t + 3, A0, Bb0);

    WAITV8; BAR; SB0;
    computeT(A1, Bb1);
    SB0; LGKM0; BAR;
    stageT(t + 4, A1, Bb1);

    WAITV8; BAR; SB0;
    computeT(A2, Bb2);
    SB0; LGKM0; BAR;
    stageT(t + 5, A2, Bb2);
  }
  WAITV8; BAR; SB0;
  computeT(A0, Bb0);
  WAITV4; BAR; SB0;
  computeT(A1, Bb1);
  WAITV0; BAR; SB0;
  computeT(A2, Bb2);

  const int g4 = (lane >> 4) << 2;
  #pragma unroll
  for (int fr = 0; fr < 4; fr++) {
    #pragma unroll
    for (int fn = 0; fn < 4; fn++) {
      const int jl = j0 + wn + fn * 16 + (lane & 15);
      const int mb = m0 + wm + fr * 16 + g4;
      const float bv = bias[jl];
      #pragma unroll
      for (int r = 0; r < 4; r++)
        outF[(size_t)(mb + r) * CD + jl] = acc[fr][fn][r] + bv;
    }
  }
}

// ---- flash attention: 32x32 swapped QK^T, in-lane softmax, permlane PV --
// block = (b*h, 128 q rows), 4 waves x 32 q rows each, KVBLK=64 dbuf
// Q/K read from qkv [B,N,2304] (Q pre-scaled); V from blocked Vt.

__global__ __launch_bounds__(256, 4)
void attn_kernel(const unsigned short* __restrict__ qkvB,  // [B][N][2304]
                 const unsigned short* __restrict__ Vt,    // [bh][8][64][128]
                 unsigned short* __restrict__ Og) {        // [B][1024][768] bf16
  __shared__ unsigned short ldsbuf[16384];
  __shared__ float sStat[2][4][32];  // [0]=corr, [1]=lsum

  unsigned short* const K0 = ldsbuf;
  unsigned short* const V0 = ldsbuf + 4096;
  unsigned short* const K1 = ldsbuf + 8192;
  unsigned short* const V1 = ldsbuf + 12288;
  unsigned short* const Qs = ldsbuf + 8192;  // 16KB, prologue only

  const int tid = threadIdx.x;
  const int lane = tid & 63;
  const int wave = tid >> 6;
  const int half = lane >> 5;
  const int q_l = lane & 31;
  const int bh = blockIdx.x;
  const int q0 = blockIdx.y * 128;
  const int b = bh / NH, head = bh - b * NH;

  const int sr = tid >> 3;                       // staging row 0..31
  const int scs = ((tid & 7) << 4) ^ ((sr & 7) << 4);

  const char* const xb_ = (const char*)qkvB + (size_t)b * 1024 * 4608;
  const int qoff = head * 128;                   // byte offset within row
  const int koff = qoff + 1536;
  const char* const vb0 = (const char*)Vt + (size_t)bh * 131072;

  // prologue: Q (128 rows) + KV tile 0
  {
    #pragma unroll
    for (int i = 0; i < 4; i++)
      gload16(xb_ + (size_t)(q0 + sr + 32 * i) * 4608 + qoff + scs,
              (char*)Qs + (tid + 256 * i) * 16);
    gload16(xb_ + (size_t)sr * 4608 + koff + scs, (char*)K0 + tid * 16);
    gload16(xb_ + (size_t)(sr + 32) * 4608 + koff + scs, (char*)K0 + 4096 + tid * 16);
    gload16(vb0 + sr * 256 + scs, (char*)V0 + tid * 16);
    gload16(vb0 + (sr + 32) * 256 + scs, (char*)V0 + 4096 + tid * 16);
  }
  __syncthreads();

  bf16x8 qf[4];
  #pragma unroll
  for (int c = 0; c < 4; c++)
    qf[c] = lds128(Qs, wave * 32 + q_l, 32 * c + 16 * half);
  __syncthreads();  // all waves done with Qs before buf1 prefetch overwrites it

  f32x16 o0 = {}, o1 = {};
  float mrun = -1e30f, lrun = 0.f;

  for (int t = 0; t < 16; t++) {
    const unsigned short* const Kc = (t & 1) ? K1 : K0;
    const unsigned short* const Vc = (t & 1) ? V1 : V0;
    unsigned short* const Kn = (t & 1) ? K0 : K1;
    unsigned short* const Vn = (t & 1) ? V0 : V1;
    if (t < 15) {
      const int kv1 = (t + 1) * 64;
      const char* const vtile = vb0 + (kv1 >> 7) * 16384 + ((kv1 >> 6) & 1) * 128;
      gload16(xb_ + (size_t)(kv1 + sr) * 4608 + koff + scs, (char*)Kn + tid * 16);
      gload16(xb_ + (size_t)(kv1 + sr + 32) * 4608 + koff + scs,
              (char*)Kn + 4096 + tid * 16);
      gload16(vtile + sr * 256 + scs, (char*)Vn + tid * 16);
      gload16(vtile + (sr + 32) * 256 + scs, (char*)Vn + 4096 + tid * 16);
    }

    // swapped QK^T: S^T tiles; lane pair (l, l+32) holds q-row l&31's 64 scores
    f32x16 s0 = {}, s1 = {};
    #pragma unroll
    for (int c = 0; c < 4; c++) {
      bf16x8 kf0 = lds128(Kc, q_l, 32 * c + 16 * half);
      bf16x8 kf1 = lds128(Kc, 32 + q_l, 32 * c + 16 * half);
      s0 = __builtin_amdgcn_mfma_f32_32x32x16_bf16(kf0, qf[c], s0, 0, 0, 0);
      s1 = __builtin_amdgcn_mfma_f32_32x32x16_bf16(kf1, qf[c], s1, 0, 0, 0);
    }

    // row max: 31 in-lane + 1 permlane pair-combine
    float vmax = fmaxf(s0[0], s1[0]);
    #pragma unroll
    for (int r = 1; r < 16; r++) vmax = fmaxf(vmax, fmaxf(s0[r], s1[r]));
    {
      u32x2 mx = pswap(__float_as_uint(vmax), __float_as_uint(vmax));
      vmax = fmaxf(__uint_as_float(mx[0]), __uint_as_float(mx[1]));
    }

    // defer-max (T13): rescale only when some row grew past THR=8 (log2 units)
    if (!__all(vmax <= mrun + 8.0f)) {
      const float mnew = fmaxf(mrun, vmax);
      const float corr = __builtin_amdgcn_exp2f(mrun - mnew);
      mrun = mnew;
      lrun *= corr;
      if (lane < 32) sStat[0][wave][q_l] = corr;
      f32x4 c4[4];
      #pragma unroll
      for (int j = 0; j < 4; j++)
        c4[j] = *reinterpret_cast<const f32x4*>(&sStat[0][wave][4 * half + 8 * j]);
      #pragma unroll
      for (int r = 0; r < 16; r++) {
        const float cc = c4[r >> 2][r & 3];
        o0[r] *= cc;
        o1[r] *= cc;
      }
    }

    // P = exp2(S - m), row-sum
    float tsum = 0.f;
    #pragma unroll
    for (int r = 0; r < 16; r++) {
      const float p0 = __builtin_amdgcn_exp2f(s0[r] - mrun);
      const float p1 = __builtin_amdgcn_exp2f(s1[r] - mrun);
      s0[r] = p0; s1[r] = p1;
      tsum += p0 + p1;
    }
    {
      u32x2 ts = pswap(__float_as_uint(tsum), __float_as_uint(tsum));
      tsum = __uint_as_float(ts[0]) + __uint_as_float(ts[1]);
    }
    lrun += tsum;

    // pack P to bf16 pair-words
    unsigned pk[2][8];
    #pragma unroll
    for (int w = 0; w < 8; w++) {
      asm("v_cvt_pk_bf16_f32 %0, %1, %2"
          : "=v"(pk[0][w]) : "v"(s0[2 * w]), "v"(s0[2 * w + 1]));
      asm("v_cvt_pk_bf16_f32 %0, %1, %2"
          : "=v"(pk[1][w]) : "v"(s1[2 * w]), "v"(s1[2 * w + 1]));
    }

    // PV: per kv-chunk c, 2 permlane swaps build the A-fragment (T12)
    #pragma unroll
    for (int c = 0; c < 4; c++) {
      const int st = c >> 1, cc = c & 1;
      u32x2 rA = pswap(pk[st][4 * cc + 0], pk[st][4 * cc + 2]);
      u32x2 rB = pswap(pk[st][4 * cc + 1], pk[st][4 * cc + 3]);
      union { unsigned u[4]; bf16x8 v; } pa;
      pa.u[0] = rA[0]; pa.u[1] = rB[0]; pa.u[2] = rA[1]; pa.u[3] = rB[1];
      bf16x8 vf0 = lds128(Vc, q_l, 32 * c + 16 * half);
      bf16x8 vf1 = lds128(Vc, 32 + q_l, 32 * c + 16 * half);
      o0 = __builtin_amdgcn_mfma_f32_32x32x16_bf16(pa.v, vf0, o0, 0, 0, 0);
      o1 = __builtin_amdgcn_mfma_f32_32x32x16_bf16(pa.v, vf1, o1, 0, 0, 0);
    }
    __syncthreads();
  }

  // epilogue: 1/l per O-reg q via per-wave stat buffer (broadcast reads)
  if (lane < 32) sStat[1][wave][q_l] = lrun;
  f32x4 rl4[4];
  #pragma unroll
  for (int j = 0; j < 4; j++) {
    f32x4 lv = *reinterpret_cast<const f32x4*>(&sStat[1][wave][4 * half + 8 * j]);
    #pragma unroll
    for (int e = 0; e < 4; e++) rl4[j][e] = __builtin_amdgcn_rcpf(lv[e]);
  }
  #pragma unroll
  for (int r = 0; r < 16; r++) {
    const int qq = q0 + wave * 32 + (r & 3) + 8 * (r >> 2) + 4 * half;
    const float rl = rl4[r >> 2][r & 3];
    const size_t base = ((size_t)b * SEQ + qq) * CD + head * HD_;
    Og[base + q_l]      = f2bf(o0[r] * rl);
    Og[base + 32 + q_l] = f2bf(o1[r] * rl);
  }
}

// ---- launch -------------------------------------------------------------

extern "C" void kernel_launch(void* const* d_in, const int* in_sizes, int n_in,
                              void* d_out, int out_size, void* d_ws, size_t ws_size,
                              hipStream_t stream) {
  const float* x     = (const float*)d_in[0];
  const float* Wqkv  = (const float*)d_in[1];
  const float* Wproj = (const float*)d_in[2];
  const float* bproj = (const float*)d_in[3];

  char* ws = (char*)d_ws;
  unsigned short* qkvB = (unsigned short*)(ws + 0);          // 75,497,472
  unsigned short* Vt   = (unsigned short*)(ws + 75497472);   // 25,165,824
  unsigned short* xb   = (unsigned short*)(ws + 100663296);  // 25,165,824
  unsigned short* ao   = (unsigned short*)(ws + 100663296);  // aliases xb (xb dead)
  unsigned short* wqT  = (unsigned short*)(ws + 125829120);  //  3,538,944
  unsigned short* wpT  = (unsigned short*)(ws + 129368064);  //  1,179,648
  if (ws_size < 130547712ull) return;

  prep_kernel<<<14592, 256, 0, stream>>>(x, Wqkv, Wproj, xb, wqT, wpT);
  gemm_qkv_kernel<<<dim3(128, 9), 256, 0, stream>>>(xb, wqT, qkvB, Vt);
  attn_kernel<<<dim3(B_ * NH, SEQ / 128), 256, 0, stream>>>(qkvB, Vt, ao);
  gemm128_kernel<1><<<dim3(128, 6), 256, 0, stream>>>(ao, wpT, (float*)d_out, bproj);
}

// Round 12
// 186.369 us; speedup vs baseline: 1.6323x; 1.0183x over previous
//
#include <hip/hip_runtime.h>

#define B_   16
#define NH   12
#define SEQ  1024
#define CD   768
#define HD_  64
#define MTOT (B_ * SEQ)
// 1/sqrt(64) * log2(e): QK^T scores land in log2 domain for exp2
#define QSCALE 0.18033688f

typedef __attribute__((ext_vector_type(4)))  float  f32x4;
typedef __attribute__((ext_vector_type(16))) float  f32x16;
typedef __attribute__((ext_vector_type(8)))  __bf16 bf16x8;
typedef __attribute__((ext_vector_type(2)))  unsigned u32x2;

#define WAITV12 asm volatile("s_waitcnt vmcnt(12)" ::: "memory")
#define WAITV8  asm volatile("s_waitcnt vmcnt(8)" ::: "memory")
#define WAITV6  asm volatile("s_waitcnt vmcnt(6)" ::: "memory")
#define WAITV4  asm volatile("s_waitcnt vmcnt(4)" ::: "memory")
#define WAITV0  asm volatile("s_waitcnt vmcnt(0)" ::: "memory")
#define LGKM0   asm volatile("s_waitcnt lgkmcnt(0)" ::: "memory")
#define BAR     __builtin_amdgcn_s_barrier()
#define SB0     __builtin_amdgcn_sched_barrier(0)

__device__ __forceinline__ unsigned short f2bf(float f) {
  unsigned u = __float_as_uint(f);
  u = (u + 0x7FFFu + ((u >> 16) & 1u)) >> 16;  // RNE
  return (unsigned short)u;
}

__device__ __forceinline__ void gload16(const void* g, void* l) {
  __builtin_amdgcn_global_load_lds(
      (const __attribute__((address_space(1))) void*)g,
      (__attribute__((address_space(3))) void*)l, 16, 0, 0);
}

__device__ __forceinline__ u32x2 pswap(unsigned x, unsigned y) {
  return __builtin_amdgcn_permlane32_swap(x, y, false, false);
}

// ---- merged prep: x f32->bf16 + both weight transpose-converts ----------

__global__ __launch_bounds__(256)
void prep_kernel(const float* __restrict__ x,
                 const float* __restrict__ Wqkv,
                 const float* __restrict__ Wproj,
                 unsigned short* __restrict__ xb,
                 unsigned short* __restrict__ wqT,
                 unsigned short* __restrict__ wpT) {
  __shared__ float tile[32][33];
  const int bid = blockIdx.x;
  const int tid = threadIdx.x;
  if (bid < 12288) {
    const int i = bid * 256 + tid;                 // n4 = 3145728 exact
    float4 f = reinterpret_cast<const float4*>(x)[i];
    uint2 o;
    o.x = (unsigned)f2bf(f.x) | ((unsigned)f2bf(f.y) << 16);
    o.y = (unsigned)f2bf(f.z) | ((unsigned)f2bf(f.w) << 16);
    reinterpret_cast<uint2*>(xb)[i] = o;
  } else {
    const float* W;
    unsigned short* Wt;
    int N, b2;
    if (bid < 12288 + 1728) { b2 = bid - 12288; W = Wqkv; Wt = wqT; N = 2304; }
    else                    { b2 = bid - 14016; W = Wproj; Wt = wpT; N = 768; }
    const int nb = N / 32;
    const int j0 = (b2 % nb) * 32, k0 = (b2 / nb) * 32;
    const int tx = tid & 31, ty = tid >> 5;
    #pragma unroll
    for (int i = 0; i < 4; i++)
      tile[ty + 8 * i][tx] = W[(size_t)(k0 + ty + 8 * i) * N + j0 + tx];
    __syncthreads();
    #pragma unroll
    for (int i = 0; i < 4; i++)
      Wt[(size_t)(j0 + ty + 8 * i) * 768 + k0 + tx] = f2bf(tile[tx][ty + 8 * i]);
  }
}

// ---- LDS fragment loads -------------------------------------------------

// 64B rows, swizzle ((row>>1)&3)<<4  (GEMM staging buffers)
__device__ __forceinline__ bf16x8 ldsA64(const unsigned short* buf, int row, int g) {
  int byte = (row << 6) + ((g << 4) ^ (((row >> 1) & 3) << 4));
  return *reinterpret_cast<const bf16x8*>((const char*)buf + byte);
}
// 128B rows, swizzle (row&7)<<4  (attention tiles)
__device__ __forceinline__ bf16x8 lds128(const unsigned short* buf, int row, int cb) {
  int byte = (row << 7) + (cb ^ ((row & 7) << 4));
  return *reinterpret_cast<const bf16x8*>((const char*)buf + byte);
}

// ---- QKV GEMM: 128m x 256n tile, 4 waves (each owns 128x64), ring-3 -----
// qkv[M][2304] bf16 (Q pre-scaled) + V^T blocked Vt[bh][8][64][128].
// Grid: 1152 blocks, XCD-swizzled (T1), m-major within XCD chunk so each
// XCD keeps a 16-m-tile A panel (3.1MB) L2-resident across j-panels.

__global__ __launch_bounds__(256, 2)
void gemm_qkv_kernel(const unsigned short* __restrict__ A,    // xb [16384][768]
                     const unsigned short* __restrict__ Bt,   // wqT [2304][768]
                     unsigned short* __restrict__ qkvOut,     // [16384][2304]
                     unsigned short* __restrict__ vtOut) {    // [192][8][64][128]
  constexpr int K = 768;
  // 72KB: A slots 3x8KB at u16 {0,4096,8192}; B slots 3x16KB at {12288,20480,28672}
  __shared__ unsigned short sbuf[36864];

  const int tid = threadIdx.x;
  const int lane = tid & 63;
  const int wave = tid >> 6;                      // wn: n-cols [wave*64, +64)
  // XCD swizzle: 1152 blocks, chunk 144/XCD; sw = m*9 + j (m-major in chunk)
  const int raw = blockIdx.x;
  const int sw = (raw & 7) * 144 + (raw >> 3);
  const int m0 = (sw / 9) << 7;
  const int j0 = (sw % 9) << 8;                   // 256-wide panel (section-aligned)

  const int sr = tid >> 2;                        // staging row 0..63
  const int sc = (tid & 3) << 4;
  const int scs = sc ^ (((sr >> 1) & 3) << 4);    // pre-swizzled source col

  f32x4 acc[8][4] = {};

  const char* const aSrc = (const char*)(A  + (size_t)(m0 + sr) * K) + scs;
  const char* const bSrc = (const char*)(Bt + (size_t)(j0 + sr) * K) + scs;

  auto stageT = [&](int kt, int slot) {
    const int kb = kt * 64;                       // 32 u16 along K
    char* ad = (char*)sbuf + slot * 8192 + tid * 16;
    char* bd = (char*)sbuf + 24576 + slot * 16384 + tid * 16;
    gload16(aSrc + kb, ad);                       // A rows sr, sr+64
    gload16(aSrc + kb + 98304, ad + 4096);
    #pragma unroll
    for (int p = 0; p < 4; p++)                   // B rows sr+64p
      gload16(bSrc + kb + p * 98304, bd + p * 4096);
  };

  const int g = lane >> 4;
  const int rl = lane & 15;

  auto computeT = [&](int slot) {
    const unsigned short* As = sbuf + slot * 4096;
    const unsigned short* Bs = sbuf + 12288 + slot * 8192;
    bf16x8 bf[4], af[8];
    #pragma unroll
    for (int fn = 0; fn < 4; fn++) bf[fn] = ldsA64(Bs, wave * 64 + fn * 16 + rl, g);
    #pragma unroll
    for (int fr = 0; fr < 8; fr++) af[fr] = ldsA64(As, fr * 16 + rl, g);
    #pragma unroll
    for (int fr = 0; fr < 8; fr++)
      #pragma unroll
      for (int fn = 0; fn < 4; fn++)
        acc[fr][fn] = __builtin_amdgcn_mfma_f32_16x16x32_bf16(af[fr], bf[fn],
                                                              acc[fr][fn], 0, 0, 0);
  };

  // prologue: 3 slots in flight (18 loads/thread)
  stageT(0, 0);
  stageT(1, 1);
  stageT(2, 2);

  #pragma unroll 1
  for (int t = 0; t < 21; t += 3) {
    WAITV12; BAR; SB0;
    computeT(0);
    SB0; LGKM0; BAR;
    stageT(t + 3, 0);

    WAITV12; BAR; SB0;
    computeT(1);
    SB0; LGKM0; BAR;
    stageT(t + 4, 1);

    WAITV12; BAR; SB0;
    computeT(2);
    SB0; LGKM0; BAR;
    stageT(t + 5, 2);
  }
  // tail: K-steps 21,22,23
  WAITV12; BAR; SB0;
  computeT(0);
  WAITV6; BAR; SB0;
  computeT(1);
  WAITV0; BAR; SB0;
  computeT(2);

  // ---- LDS-coalesced epilogue ----
  const int g4 = g << 2;
  BAR;                                            // all waves done with slots
  const bool secV = (j0 >= 1536);
  const float scale = (j0 < 768) ? QSCALE : 1.0f;
  char* const ct = (char*)sbuf;
  if (!secV) {
    // m-major ctile: 128 rows x 528B (256 j + 16B pad)
    #pragma unroll
    for (int fr = 0; fr < 8; fr++)
      #pragma unroll
      for (int fn = 0; fn < 4; fn++) {
        const int j_l = wave * 64 + fn * 16 + rl;
        const int mb = fr * 16 + g4;
        #pragma unroll
        for (int r = 0; r < 4; r++)
          *reinterpret_cast<unsigned short*>(ct + (mb + r) * 528 + j_l * 2) =
              f2bf(acc[fr][fn][r] * scale);
      }
  } else {
    // j-major ctile: 256 rows x 264B (128 m + 8B pad), packed 8B writes
    #pragma unroll
    for (int fr = 0; fr < 8; fr++)
      #pragma unroll
      for (int fn = 0; fn < 4; fn++) {
        const int j_l = wave * 64 + fn * 16 + rl;
        const int mb = fr * 16 + g4;
        uint2 pkd;
        pkd.x = (unsigned)f2bf(acc[fr][fn][0]) | ((unsigned)f2bf(acc[fr][fn][1]) << 16);
        pkd.y = (unsigned)f2bf(acc[fr][fn][2]) | ((unsigned)f2bf(acc[fr][fn][3]) << 16);
        *reinterpret_cast<uint2*>(ct + j_l * 264 + mb * 2) = pkd;
      }
  }
  LGKM0; BAR;
  if (!secV) {
    const int c = tid & 31, r0 = tid >> 5;        // 32 x 16B chunks per row
    char* const gb = (char*)qkvOut + (size_t)m0 * 4608 + j0 * 2 + c * 16;
    #pragma unroll
    for (int k = 0; k < 16; k++) {
      const int row = r0 + 8 * k;
      const uint4 d = *reinterpret_cast<const uint4*>(ct + row * 528 + c * 16);
      *reinterpret_cast<uint4*>(gb + (size_t)row * 4608) = d;
    }
  } else {
    const int c = tid & 15, r0 = tid >> 4;        // 16 x 16B chunks per row
    const int bidx = m0 >> 10;
    const int nblk = (m0 & 1023) >> 7;
    #pragma unroll
    for (int k = 0; k < 16; k++) {
      const int jr = r0 + 16 * k;
      const int h = ((j0 - 1536) >> 6) + (jr >> 6);
      const int d = jr & 63;
      const size_t dst = ((size_t)((bidx * NH + h) * 8 + nblk) * 64 + d) * 256 + c * 16;
      const uint4 v = *reinterpret_cast<const uint4*>(ct + jr * 264 + c * 16);
      *reinterpret_cast<uint4*>((char*)vtOut + dst) = v;
    }
  }
}

// ---- proj GEMM: 128x128 depth-3 ring, direct f32 + bias epilogue --------
// Grid 768, XCD-swizzled: chunk 96/XCD, sw = m*6 + j.

template <int MODE>
__global__ __launch_bounds__(256, 3)
void gemm128_kernel(const unsigned short* __restrict__ A,
                    const unsigned short* __restrict__ Bt,
                    float* __restrict__ outF,
                    const float* __restrict__ bias) {
  constexpr int K = 768;
  __shared__ unsigned short sbuf[24576];  // 48KB = 3 x (A 8KB + B 8KB)
  unsigned short* const A0 = sbuf;
  unsigned short* const Bb0 = sbuf + 4096;
  unsigned short* const A1 = sbuf + 8192;
  unsigned short* const Bb1 = sbuf + 12288;
  unsigned short* const A2 = sbuf + 16384;
  unsigned short* const Bb2 = sbuf + 20480;

  const int tid = threadIdx.x;
  const int lane = tid & 63;
  const int wave = tid >> 6;
  const int wm = (wave >> 1) << 6;
  const int wn = (wave & 1) << 6;
  const int raw = blockIdx.x;
  const int sw = (raw & 7) * 96 + (raw >> 3);
  const int m0 = (sw / 6) << 7;
  const int j0 = (sw % 6) << 7;

  const int sr = tid >> 2;
  const int sc = (tid & 3) << 4;
  const int scs = sc ^ (((sr >> 1) & 3) << 4);

  f32x4 acc[4][4] = {};

  const char* const ab  = (const char*)(A  + (size_t)(m0 + sr) * K) + scs;
  const char* const ab2 = (const char*)(A  + (size_t)(m0 + sr + 64) * K) + scs;
  const char* const bb  = (const char*)(Bt + (size_t)(j0 + sr) * K) + scs;
  const char* const bb2 = (const char*)(Bt + (size_t)(j0 + sr + 64) * K) + scs;

  auto stageT = [&](int kt, unsigned short* Ad, unsigned short* Bd) {
    const int kb = kt * 64;
    gload16(ab  + kb, (char*)Ad + tid * 16);
    gload16(ab2 + kb, (char*)Ad + 4096 + tid * 16);
    gload16(bb  + kb, (char*)Bd + tid * 16);
    gload16(bb2 + kb, (char*)Bd + 4096 + tid * 16);
  };

  auto computeT = [&](const unsigned short* As, const unsigned short* Bs) {
    bf16x8 af[4], bf[4];
    const int g = lane >> 4;
    #pragma unroll
    for (int fr = 0; fr < 4; fr++) af[fr] = ldsA64(As, wm + fr * 16 + (lane & 15), g);
    #pragma unroll
    for (int fn = 0; fn < 4; fn++) bf[fn] = ldsA64(Bs, wn + fn * 16 + (lane & 15), g);
    #pragma unroll
    for (int fr = 0; fr < 4; fr++)
      #pragma unroll
      for (int fn = 0; fn < 4; fn++)
        acc[fr][fn] = __builtin_amdgcn_mfma_f32_16x16x32_bf16(af[fr], bf[fn],
                                                              acc[fr][fn], 0, 0, 0);
  };

  stageT(0, A0, Bb0);
  stageT(1, A1, Bb1);
  stageT(2, A2, Bb2);

  #pragma unroll 1
  for (int t = 0; t < 21; t += 3) {
    WAITV8; BAR; SB0;
    computeT(A0, Bb0);
    SB0; LGKM0; BAR;
    stageT(t + 3, A0, Bb0);

    WAITV8; BAR; SB0;
    computeT(A1, Bb1);
    SB0; LGKM0; BAR;
    stageT(t + 4, A1, Bb1);

    WAITV8; BAR; SB0;
    computeT(A2, Bb2);
    SB0; LGKM0; BAR;
    stageT(t + 5, A2, Bb2);
  }
  WAITV8; BAR; SB0;
  computeT(A0, Bb0);
  WAITV4; BAR; SB0;
  computeT(A1, Bb1);
  WAITV0; BAR; SB0;
  computeT(A2, Bb2);

  const int g4 = (lane >> 4) << 2;
  #pragma unroll
  for (int fr = 0; fr < 4; fr++) {
    #pragma unroll
    for (int fn = 0; fn < 4; fn++) {
      const int jl = j0 + wn + fn * 16 + (lane & 15);
      const int mb = m0 + wm + fr * 16 + g4;
      const float bv = bias[jl];
      #pragma unroll
      for (int r = 0; r < 4; r++)
        outF[(size_t)(mb + r) * CD + jl] = acc[fr][fn][r] + bv;
    }
  }
}

// ---- flash attention: 32x32 swapped QK^T, in-lane softmax, permlane PV --
// block = (b*h, 128 q rows), 4 waves x 32 q rows each, KVBLK=64 dbuf
// Grid 1536, XCD-swizzled with q0 fast: all 8 q0-blocks of one bh share an
// XCD's L2 (KV = 256KB resident).

__global__ __launch_bounds__(256, 4)
void attn_kernel(const unsigned short* __restrict__ qkvB,  // [B][N][2304]
                 const unsigned short* __restrict__ Vt,    // [bh][8][64][128]
                 unsigned short* __restrict__ Og) {        // [B][1024][768] bf16
  __shared__ unsigned short ldsbuf[16384];
  __shared__ float sStat[2][4][32];  // [0]=corr, [1]=lsum

  unsigned short* const K0 = ldsbuf;
  unsigned short* const V0 = ldsbuf + 4096;
  unsigned short* const K1 = ldsbuf + 8192;
  unsigned short* const V1 = ldsbuf + 12288;
  unsigned short* const Qs = ldsbuf + 8192;  // 16KB, prologue only

  const int tid = threadIdx.x;
  const int lane = tid & 63;
  const int wave = tid >> 6;
  const int half = lane >> 5;
  const int q_l = lane & 31;
  const int raw = blockIdx.x;
  const int sw = (raw & 7) * 192 + (raw >> 3);
  const int bh = sw >> 3;
  const int q0 = (sw & 7) * 128;
  const int b = bh / NH, head = bh - b * NH;

  const int sr = tid >> 3;                       // staging row 0..31
  const int scs = ((tid & 7) << 4) ^ ((sr & 7) << 4);

  const char* const xb_ = (const char*)qkvB + (size_t)b * 1024 * 4608;
  const int qoff = head * 128;                   // byte offset within row
  const int koff = qoff + 1536;
  const char* const vb0 = (const char*)Vt + (size_t)bh * 131072;

  // prologue: Q (128 rows) + KV tile 0
  {
    #pragma unroll
    for (int i = 0; i < 4; i++)
      gload16(xb_ + (size_t)(q0 + sr + 32 * i) * 4608 + qoff + scs,
              (char*)Qs + (tid + 256 * i) * 16);
    gload16(xb_ + (size_t)sr * 4608 + koff + scs, (char*)K0 + tid * 16);
    gload16(xb_ + (size_t)(sr + 32) * 4608 + koff + scs, (char*)K0 + 4096 + tid * 16);
    gload16(vb0 + sr * 256 + scs, (char*)V0 + tid * 16);
    gload16(vb0 + (sr + 32) * 256 + scs, (char*)V0 + 4096 + tid * 16);
  }
  __syncthreads();

  bf16x8 qf[4];
  #pragma unroll
  for (int c = 0; c < 4; c++)
    qf[c] = lds128(Qs, wave * 32 + q_l, 32 * c + 16 * half);
  __syncthreads();  // all waves done with Qs before buf1 prefetch overwrites it

  f32x16 o0 = {}, o1 = {};
  float mrun = -1e30f, lrun = 0.f;

  for (int t = 0; t < 16; t++) {
    const unsigned short* const Kc = (t & 1) ? K1 : K0;
    const unsigned short* const Vc = (t & 1) ? V1 : V0;
    unsigned short* const Kn = (t & 1) ? K0 : K1;
    unsigned short* const Vn = (t & 1) ? V0 : V1;
    if (t < 15) {
      const int kv1 = (t + 1) * 64;
      const char* const vtile = vb0 + (kv1 >> 7) * 16384 + ((kv1 >> 6) & 1) * 128;
      gload16(xb_ + (size_t)(kv1 + sr) * 4608 + koff + scs, (char*)Kn + tid * 16);
      gload16(xb_ + (size_t)(kv1 + sr + 32) * 4608 + koff + scs,
              (char*)Kn + 4096 + tid * 16);
      gload16(vtile + sr * 256 + scs, (char*)Vn + tid * 16);
      gload16(vtile + (sr + 32) * 2048 / 8 + scs, (char*)Vn + 4096 + tid * 16);
    }

    // swapped QK^T: S^T tiles; lane pair (l, l+32) holds q-row l&31's 64 scores
    f32x16 s0 = {}, s1 = {};
    #pragma unroll
    for (int c = 0; c < 4; c++) {
      bf16x8 kf0 = lds128(Kc, q_l, 32 * c + 16 * half);
      bf16x8 kf1 = lds128(Kc, 32 + q_l, 32 * c + 16 * half);
      s0 = __builtin_amdgcn_mfma_f32_32x32x16_bf16(kf0, qf[c], s0, 0, 0, 0);
      s1 = __builtin_amdgcn_mfma_f32_32x32x16_bf16(kf1, qf[c], s1, 0, 0, 0);
    }

    // row max: 31 in-lane + 1 permlane pair-combine
    float vmax = fmaxf(s0[0], s1[0]);
    #pragma unroll
    for (int r = 1; r < 16; r++) vmax = fmaxf(vmax, fmaxf(s0[r], s1[r]));
    {
      u32x2 mx = pswap(__float_as_uint(vmax), __float_as_uint(vmax));
      vmax = fmaxf(__uint_as_float(mx[0]), __uint_as_float(mx[1]));
    }

    // defer-max (T13): rescale only when some row grew past THR=8 (log2 units)
    if (!__all(vmax <= mrun + 8.0f)) {
      const float mnew = fmaxf(mrun, vmax);
      const float corr = __builtin_amdgcn_exp2f(mrun - mnew);
      mrun = mnew;
      lrun *= corr;
      if (lane < 32) sStat[0][wave][q_l] = corr;
      f32x4 c4[4];
      #pragma unroll
      for (int j = 0; j < 4; j++)
        c4[j] = *reinterpret_cast<const f32x4*>(&sStat[0][wave][4 * half + 8 * j]);
      #pragma unroll
      for (int r = 0; r < 16; r++) {
        const float cc = c4[r >> 2][r & 3];
        o0[r] *= cc;
        o1[r] *= cc;
      }
    }

    // P = exp2(S - m), row-sum
    float tsum = 0.f;
    #pragma unroll
    for (int r = 0; r < 16; r++) {
      const float p0 = __builtin_amdgcn_exp2f(s0[r] - mrun);
      const float p1 = __builtin_amdgcn_exp2f(s1[r] - mrun);
      s0[r] = p0; s1[r] = p1;
      tsum += p0 + p1;
    }
    {
      u32x2 ts = pswap(__float_as_uint(tsum), __float_as_uint(tsum));
      tsum = __uint_as_float(ts[0]) + __uint_as_float(ts[1]);
    }
    lrun += tsum;

    // pack P to bf16 pair-words
    unsigned pk[2][8];
    #pragma unroll
    for (int w = 0; w < 8; w++) {
      asm("v_cvt_pk_bf16_f32 %0, %1, %2"
          : "=v"(pk[0][w]) : "v"(s0[2 * w]), "v"(s0[2 * w + 1]));
      asm("v_cvt_pk_bf16_f32 %0, %1, %2"
          : "=v"(pk[1][w]) : "v"(s1[2 * w]), "v"(s1[2 * w + 1]));
    }

    // PV: per kv-chunk c, 2 permlane swaps build the A-fragment (T12)
    #pragma unroll
    for (int c = 0; c < 4; c++) {
      const int st = c >> 1, cc = c & 1;
      u32x2 rA = pswap(pk[st][4 * cc + 0], pk[st][4 * cc + 2]);
      u32x2 rB = pswap(pk[st][4 * cc + 1], pk[st][4 * cc + 3]);
      union { unsigned u[4]; bf16x8 v; } pa;
      pa.u[0] = rA[0]; pa.u[1] = rB[0]; pa.u[2] = rA[1]; pa.u[3] = rB[1];
      bf16x8 vf0 = lds128(Vc, q_l, 32 * c + 16 * half);
      bf16x8 vf1 = lds128(Vc, 32 + q_l, 32 * c + 16 * half);
      o0 = __builtin_amdgcn_mfma_f32_32x32x16_bf16(pa.v, vf0, o0, 0, 0, 0);
      o1 = __builtin_amdgcn_mfma_f32_32x32x16_bf16(pa.v, vf1, o1, 0, 0, 0);
    }
    __syncthreads();
  }

  // epilogue: 1/l per O-reg q via per-wave stat buffer (broadcast reads)
  if (lane < 32) sStat[1][wave][q_l] = lrun;
  f32x4 rl4[4];
  #pragma unroll
  for (int j = 0; j < 4; j++) {
    f32x4 lv = *reinterpret_cast<const f32x4*>(&sStat[1][wave][4 * half + 8 * j]);
    #pragma unroll
    for (int e = 0; e < 4; e++) rl4[j][e] = __builtin_amdgcn_rcpf(lv[e]);
  }
  #pragma unroll
  for (int r = 0; r < 16; r++) {
    const int qq = q0 + wave * 32 + (r & 3) + 8 * (r >> 2) + 4 * half;
    const float rl = rl4[r >> 2][r & 3];
    const size_t base = ((size_t)b * SEQ + qq) * CD + head * HD_;
    Og[base + q_l]      = f2bf(o0[r] * rl);
    Og[base + 32 + q_l] = f2bf(o1[r] * rl);
  }
}

// ---- launch -------------------------------------------------------------

extern "C" void kernel_launch(void* const* d_in, const int* in_sizes, int n_in,
                              void* d_out, int out_size, void* d_ws, size_t ws_size,
                              hipStream_t stream) {
  const float* x     = (const float*)d_in[0];
  const float* Wqkv  = (const float*)d_in[1];
  const float* Wproj = (const float*)d_in[2];
  const float* bproj = (const float*)d_in[3];

  char* ws = (char*)d_ws;
  unsigned short* qkvB = (unsigned short*)(ws + 0);          // 75,497,472
  unsigned short* Vt   = (unsigned short*)(ws + 75497472);   // 25,165,824
  unsigned short* xb   = (unsigned short*)(ws + 100663296);  // 25,165,824
  unsigned short* ao   = (unsigned short*)(ws + 100663296);  // aliases xb (xb dead)
  unsigned short* wqT  = (unsigned short*)(ws + 125829120);  //  3,538,944
  unsigned short* wpT  = (unsigned short*)(ws + 129368064);  //  1,179,648
  if (ws_size < 130547712ull) return;

  prep_kernel<<<14592, 256, 0, stream>>>(x, Wqkv, Wproj, xb, wqT, wpT);
  gemm_qkv_kernel<<<1152, 256, 0, stream>>>(xb, wqT, qkvB, Vt);
  attn_kernel<<<1536, 256, 0, stream>>>(qkvB, Vt, ao);
  gemm128_kernel<1><<<768, 256, 0, stream>>>(ao, wpT, (float*)d_out, bproj);
}

// Round 14
// 186.242 us; speedup vs baseline: 1.6334x; 1.0007x over previous
//
#include <hip/hip_runtime.h>

#define B_   16
#define NH   12
#define SEQ  1024
#define CD   768
#define HD_  64
#define MTOT (B_ * SEQ)
// 1/sqrt(64) * log2(e): QK^T scores land in log2 domain for exp2
#define QSCALE 0.18033688f

typedef __attribute__((ext_vector_type(4)))  float  f32x4;
typedef __attribute__((ext_vector_type(16))) float  f32x16;
typedef __attribute__((ext_vector_type(8)))  __bf16 bf16x8;
typedef __attribute__((ext_vector_type(2)))  unsigned u32x2;

#define WAITV12 asm volatile("s_waitcnt vmcnt(12)" ::: "memory")
#define WAITV8  asm volatile("s_waitcnt vmcnt(8)" ::: "memory")
#define WAITV6  asm volatile("s_waitcnt vmcnt(6)" ::: "memory")
#define WAITV4  asm volatile("s_waitcnt vmcnt(4)" ::: "memory")
#define WAITV0  asm volatile("s_waitcnt vmcnt(0)" ::: "memory")
#define LGKM0   asm volatile("s_waitcnt lgkmcnt(0)" ::: "memory")
#define BAR     __builtin_amdgcn_s_barrier()
#define SB0     __builtin_amdgcn_sched_barrier(0)

__device__ __forceinline__ unsigned short f2bf(float f) {
  unsigned u = __float_as_uint(f);
  u = (u + 0x7FFFu + ((u >> 16) & 1u)) >> 16;  // RNE
  return (unsigned short)u;
}

__device__ __forceinline__ void gload16(const void* g, void* l) {
  __builtin_amdgcn_global_load_lds(
      (const __attribute__((address_space(1))) void*)g,
      (__attribute__((address_space(3))) void*)l, 16, 0, 0);
}

__device__ __forceinline__ u32x2 pswap(unsigned x, unsigned y) {
  return __builtin_amdgcn_permlane32_swap(x, y, false, false);
}

// ---- merged prep: x f32->bf16 + both weight transpose-converts ----------

__global__ __launch_bounds__(256)
void prep_kernel(const float* __restrict__ x,
                 const float* __restrict__ Wqkv,
                 const float* __restrict__ Wproj,
                 unsigned short* __restrict__ xb,
                 unsigned short* __restrict__ wqT,
                 unsigned short* __restrict__ wpT) {
  __shared__ float tile[32][33];
  const int bid = blockIdx.x;
  const int tid = threadIdx.x;
  if (bid < 12288) {
    const int i = bid * 256 + tid;                 // n4 = 3145728 exact
    float4 f = reinterpret_cast<const float4*>(x)[i];
    uint2 o;
    o.x = (unsigned)f2bf(f.x) | ((unsigned)f2bf(f.y) << 16);
    o.y = (unsigned)f2bf(f.z) | ((unsigned)f2bf(f.w) << 16);
    reinterpret_cast<uint2*>(xb)[i] = o;
  } else {
    const float* W;
    unsigned short* Wt;
    int N, b2;
    if (bid < 12288 + 1728) { b2 = bid - 12288; W = Wqkv; Wt = wqT; N = 2304; }
    else                    { b2 = bid - 14016; W = Wproj; Wt = wpT; N = 768; }
    const int nb = N / 32;
    const int j0 = (b2 % nb) * 32, k0 = (b2 / nb) * 32;
    const int tx = tid & 31, ty = tid >> 5;
    #pragma unroll
    for (int i = 0; i < 4; i++)
      tile[ty + 8 * i][tx] = W[(size_t)(k0 + ty + 8 * i) * N + j0 + tx];
    __syncthreads();
    #pragma unroll
    for (int i = 0; i < 4; i++)
      Wt[(size_t)(j0 + ty + 8 * i) * 768 + k0 + tx] = f2bf(tile[tx][ty + 8 * i]);
  }
}

// ---- LDS fragment loads -------------------------------------------------

// 64B rows, swizzle ((row>>1)&3)<<4  (GEMM staging buffers)
__device__ __forceinline__ bf16x8 ldsA64(const unsigned short* buf, int row, int g) {
  int byte = (row << 6) + ((g << 4) ^ (((row >> 1) & 3) << 4));
  return *reinterpret_cast<const bf16x8*>((const char*)buf + byte);
}
// 128B rows, swizzle (row&7)<<4  (attention tiles)
__device__ __forceinline__ bf16x8 lds128(const unsigned short* buf, int row, int cb) {
  int byte = (row << 7) + (cb ^ ((row & 7) << 4));
  return *reinterpret_cast<const bf16x8*>((const char*)buf + byte);
}

// ---- QKV GEMM: 128m x 256n tile, 4 waves (each owns 128x64), ring-3 -----
// qkv[M][2304] bf16 (Q pre-scaled) + V^T blocked Vt[bh][8][64][128].
// Grid: 1152 blocks, XCD-swizzled (T1), m-major within XCD chunk so each
// XCD keeps a 16-m-tile A panel (3.1MB) L2-resident across j-panels.

__global__ __launch_bounds__(256, 2)
void gemm_qkv_kernel(const unsigned short* __restrict__ A,    // xb [16384][768]
                     const unsigned short* __restrict__ Bt,   // wqT [2304][768]
                     unsigned short* __restrict__ qkvOut,     // [16384][2304]
                     unsigned short* __restrict__ vtOut) {    // [192][8][64][128]
  constexpr int K = 768;
  // 72KB: A slots 3x8KB at u16 {0,4096,8192}; B slots 3x16KB at {12288,20480,28672}
  __shared__ unsigned short sbuf[36864];

  const int tid = threadIdx.x;
  const int lane = tid & 63;
  const int wave = tid >> 6;                      // wn: n-cols [wave*64, +64)
  // XCD swizzle: 1152 blocks, chunk 144/XCD; sw = m*9 + j (m-major in chunk)
  const int raw = blockIdx.x;
  const int sw = (raw & 7) * 144 + (raw >> 3);
  const int m0 = (sw / 9) << 7;
  const int j0 = (sw % 9) << 8;                   // 256-wide panel (section-aligned)

  const int sr = tid >> 2;                        // staging row 0..63
  const int sc = (tid & 3) << 4;
  const int scs = sc ^ (((sr >> 1) & 3) << 4);    // pre-swizzled source col

  f32x4 acc[8][4] = {};

  const char* const aSrc = (const char*)(A  + (size_t)(m0 + sr) * K) + scs;
  const char* const bSrc = (const char*)(Bt + (size_t)(j0 + sr) * K) + scs;

  auto stageT = [&](int kt, int slot) {
    const int kb = kt * 64;                       // 32 u16 along K
    char* ad = (char*)sbuf + slot * 8192 + tid * 16;
    char* bd = (char*)sbuf + 24576 + slot * 16384 + tid * 16;
    gload16(aSrc + kb, ad);                       // A rows sr, sr+64
    gload16(aSrc + kb + 98304, ad + 4096);
    #pragma unroll
    for (int p = 0; p < 4; p++)                   // B rows sr+64p
      gload16(bSrc + kb + p * 98304, bd + p * 4096);
  };

  const int g = lane >> 4;
  const int rl = lane & 15;

  auto computeT = [&](int slot) {
    const unsigned short* As = sbuf + slot * 4096;
    const unsigned short* Bs = sbuf + 12288 + slot * 8192;
    bf16x8 bf[4], af[8];
    #pragma unroll
    for (int fn = 0; fn < 4; fn++) bf[fn] = ldsA64(Bs, wave * 64 + fn * 16 + rl, g);
    #pragma unroll
    for (int fr = 0; fr < 8; fr++) af[fr] = ldsA64(As, fr * 16 + rl, g);
    #pragma unroll
    for (int fr = 0; fr < 8; fr++)
      #pragma unroll
      for (int fn = 0; fn < 4; fn++)
        acc[fr][fn] = __builtin_amdgcn_mfma_f32_16x16x32_bf16(af[fr], bf[fn],
                                                              acc[fr][fn], 0, 0, 0);
  };

  // prologue: 3 slots in flight (18 loads/thread)
  stageT(0, 0);
  stageT(1, 1);
  stageT(2, 2);

  #pragma unroll 1
  for (int t = 0; t < 21; t += 3) {
    WAITV12; BAR; SB0;
    computeT(0);
    SB0; LGKM0; BAR;
    stageT(t + 3, 0);

    WAITV12; BAR; SB0;
    computeT(1);
    SB0; LGKM0; BAR;
    stageT(t + 4, 1);

    WAITV12; BAR; SB0;
    computeT(2);
    SB0; LGKM0; BAR;
    stageT(t + 5, 2);
  }
  // tail: K-steps 21,22,23
  WAITV12; BAR; SB0;
  computeT(0);
  WAITV6; BAR; SB0;
  computeT(1);
  WAITV0; BAR; SB0;
  computeT(2);

  // ---- LDS-coalesced epilogue ----
  const int g4 = g << 2;
  BAR;                                            // all waves done with slots
  const bool secV = (j0 >= 1536);
  const float scale = (j0 < 768) ? QSCALE : 1.0f;
  char* const ct = (char*)sbuf;
  if (!secV) {
    // m-major ctile: 128 rows x 528B (256 j + 16B pad)
    #pragma unroll
    for (int fr = 0; fr < 8; fr++)
      #pragma unroll
      for (int fn = 0; fn < 4; fn++) {
        const int j_l = wave * 64 + fn * 16 + rl;
        const int mb = fr * 16 + g4;
        #pragma unroll
        for (int r = 0; r < 4; r++)
          *reinterpret_cast<unsigned short*>(ct + (mb + r) * 528 + j_l * 2) =
              f2bf(acc[fr][fn][r] * scale);
      }
  } else {
    // j-major ctile: 256 rows x 264B (128 m + 8B pad), packed 8B writes
    #pragma unroll
    for (int fr = 0; fr < 8; fr++)
      #pragma unroll
      for (int fn = 0; fn < 4; fn++) {
        const int j_l = wave * 64 + fn * 16 + rl;
        const int mb = fr * 16 + g4;
        uint2 pkd;
        pkd.x = (unsigned)f2bf(acc[fr][fn][0]) | ((unsigned)f2bf(acc[fr][fn][1]) << 16);
        pkd.y = (unsigned)f2bf(acc[fr][fn][2]) | ((unsigned)f2bf(acc[fr][fn][3]) << 16);
        *reinterpret_cast<uint2*>(ct + j_l * 264 + mb * 2) = pkd;
      }
  }
  LGKM0; BAR;
  if (!secV) {
    const int c = tid & 31, r0 = tid >> 5;        // 32 x 16B chunks per row
    char* const gb = (char*)qkvOut + (size_t)m0 * 4608 + j0 * 2 + c * 16;
    #pragma unroll
    for (int k = 0; k < 16; k++) {
      const int row = r0 + 8 * k;
      const uint4 d = *reinterpret_cast<const uint4*>(ct + row * 528 + c * 16);
      *reinterpret_cast<uint4*>(gb + (size_t)row * 4608) = d;
    }
  } else {
    const int c = tid & 15, r0 = tid >> 4;        // 16 x 16B chunks per row
    const int bidx = m0 >> 10;
    const int nblk = (m0 & 1023) >> 7;
    #pragma unroll
    for (int k = 0; k < 16; k++) {
      const int jr = r0 + 16 * k;
      const int h = ((j0 - 1536) >> 6) + (jr >> 6);
      const int d = jr & 63;
      const size_t dst = ((size_t)((bidx * NH + h) * 8 + nblk) * 64 + d) * 256 + c * 16;
      const uint4 v = *reinterpret_cast<const uint4*>(ct + jr * 264 + c * 16);
      *reinterpret_cast<uint4*>((char*)vtOut + dst) = v;
    }
  }
}

// ---- proj GEMM: 128x128 depth-3 ring, direct f32 + bias epilogue --------
// Grid 768, XCD-swizzled: chunk 96/XCD, sw = m*6 + j.

template <int MODE>
__global__ __launch_bounds__(256, 3)
void gemm128_kernel(const unsigned short* __restrict__ A,
                    const unsigned short* __restrict__ Bt,
                    float* __restrict__ outF,
                    const float* __restrict__ bias) {
  constexpr int K = 768;
  __shared__ unsigned short sbuf[24576];  // 48KB = 3 x (A 8KB + B 8KB)
  unsigned short* const A0 = sbuf;
  unsigned short* const Bb0 = sbuf + 4096;
  unsigned short* const A1 = sbuf + 8192;
  unsigned short* const Bb1 = sbuf + 12288;
  unsigned short* const A2 = sbuf + 16384;
  unsigned short* const Bb2 = sbuf + 20480;

  const int tid = threadIdx.x;
  const int lane = tid & 63;
  const int wave = tid >> 6;
  const int wm = (wave >> 1) << 6;
  const int wn = (wave & 1) << 6;
  const int raw = blockIdx.x;
  const int sw = (raw & 7) * 96 + (raw >> 3);
  const int m0 = (sw / 6) << 7;
  const int j0 = (sw % 6) << 7;

  const int sr = tid >> 2;
  const int sc = (tid & 3) << 4;
  const int scs = sc ^ (((sr >> 1) & 3) << 4);

  f32x4 acc[4][4] = {};

  const char* const ab  = (const char*)(A  + (size_t)(m0 + sr) * K) + scs;
  const char* const ab2 = (const char*)(A  + (size_t)(m0 + sr + 64) * K) + scs;
  const char* const bb  = (const char*)(Bt + (size_t)(j0 + sr) * K) + scs;
  const char* const bb2 = (const char*)(Bt + (size_t)(j0 + sr + 64) * K) + scs;

  auto stageT = [&](int kt, unsigned short* Ad, unsigned short* Bd) {
    const int kb = kt * 64;
    gload16(ab  + kb, (char*)Ad + tid * 16);
    gload16(ab2 + kb, (char*)Ad + 4096 + tid * 16);
    gload16(bb  + kb, (char*)Bd + tid * 16);
    gload16(bb2 + kb, (char*)Bd + 4096 + tid * 16);
  };

  auto computeT = [&](const unsigned short* As, const unsigned short* Bs) {
    bf16x8 af[4], bf[4];
    const int g = lane >> 4;
    #pragma unroll
    for (int fr = 0; fr < 4; fr++) af[fr] = ldsA64(As, wm + fr * 16 + (lane & 15), g);
    #pragma unroll
    for (int fn = 0; fn < 4; fn++) bf[fn] = ldsA64(Bs, wn + fn * 16 + (lane & 15), g);
    __builtin_amdgcn_s_setprio(1);
    #pragma unroll
    for (int fr = 0; fr < 4; fr++)
      #pragma unroll
      for (int fn = 0; fn < 4; fn++)
        acc[fr][fn] = __builtin_amdgcn_mfma_f32_16x16x32_bf16(af[fr], bf[fn],
                                                              acc[fr][fn], 0, 0, 0);
    __builtin_amdgcn_s_setprio(0);
  };

  stageT(0, A0, Bb0);
  stageT(1, A1, Bb1);
  stageT(2, A2, Bb2);

  #pragma unroll 1
  for (int t = 0; t < 21; t += 3) {
    WAITV8; BAR; SB0;
    computeT(A0, Bb0);
    SB0; LGKM0; BAR;
    stageT(t + 3, A0, Bb0);

    WAITV8; BAR; SB0;
    computeT(A1, Bb1);
    SB0; LGKM0; BAR;
    stageT(t + 4, A1, Bb1);

    WAITV8; BAR; SB0;
    computeT(A2, Bb2);
    SB0; LGKM0; BAR;
    stageT(t + 5, A2, Bb2);
  }
  WAITV8; BAR; SB0;
  computeT(A0, Bb0);
  WAITV4; BAR; SB0;
  computeT(A1, Bb1);
  WAITV0; BAR; SB0;
  computeT(A2, Bb2);

  const int g4 = (lane >> 4) << 2;
  #pragma unroll
  for (int fr = 0; fr < 4; fr++) {
    #pragma unroll
    for (int fn = 0; fn < 4; fn++) {
      const int jl = j0 + wn + fn * 16 + (lane & 15);
      const int mb = m0 + wm + fr * 16 + g4;
      const float bv = bias[jl];
      #pragma unroll
      for (int r = 0; r < 4; r++)
        outF[(size_t)(mb + r) * CD + jl] = acc[fr][fn][r] + bv;
    }
  }
}

// ---- flash attention: 32x32 swapped QK^T, in-lane softmax, permlane PV --
// block = (b*h, 128 q rows), 4 waves x 32 q rows each, KVBLK=64 dbuf
// Grid 1536, XCD-swizzled with q0 fast: all 8 q0-blocks of one bh share an
// XCD's L2 (KV = 256KB resident).

__global__ __launch_bounds__(256, 4)
void attn_kernel(const unsigned short* __restrict__ qkvB,  // [B][N][2304]
                 const unsigned short* __restrict__ Vt,    // [bh][8][64][128]
                 unsigned short* __restrict__ Og) {        // [B][1024][768] bf16
  __shared__ unsigned short ldsbuf[16384];
  __shared__ float sStat[2][4][32];  // [0]=corr, [1]=lsum

  unsigned short* const K0 = ldsbuf;
  unsigned short* const V0 = ldsbuf + 4096;
  unsigned short* const K1 = ldsbuf + 8192;
  unsigned short* const V1 = ldsbuf + 12288;
  unsigned short* const Qs = ldsbuf + 8192;  // 16KB, prologue only

  const int tid = threadIdx.x;
  const int lane = tid & 63;
  const int wave = tid >> 6;
  const int half = lane >> 5;
  const int q_l = lane & 31;
  const int raw = blockIdx.x;
  const int sw = (raw & 7) * 192 + (raw >> 3);
  const int bh = sw >> 3;
  const int q0 = (sw & 7) * 128;
  const int b = bh / NH, head = bh - b * NH;

  const int sr = tid >> 3;                       // staging row 0..31
  const int scs = ((tid & 7) << 4) ^ ((sr & 7) << 4);

  const char* const xb_ = (const char*)qkvB + (size_t)b * 1024 * 4608;
  const int qoff = head * 128;                   // byte offset within row
  const int koff = qoff + 1536;
  const char* const vb0 = (const char*)Vt + (size_t)bh * 131072;

  // prologue: Q (128 rows) + KV tile 0
  {
    #pragma unroll
    for (int i = 0; i < 4; i++)
      gload16(xb_ + (size_t)(q0 + sr + 32 * i) * 4608 + qoff + scs,
              (char*)Qs + (tid + 256 * i) * 16);
    gload16(xb_ + (size_t)sr * 4608 + koff + scs, (char*)K0 + tid * 16);
    gload16(xb_ + (size_t)(sr + 32) * 4608 + koff + scs, (char*)K0 + 4096 + tid * 16);
    gload16(vb0 + sr * 256 + scs, (char*)V0 + tid * 16);
    gload16(vb0 + (sr + 32) * 256 + scs, (char*)V0 + 4096 + tid * 16);
  }
  __syncthreads();

  bf16x8 qf[4];
  #pragma unroll
  for (int c = 0; c < 4; c++)
    qf[c] = lds128(Qs, wave * 32 + q_l, 32 * c + 16 * half);
  __syncthreads();  // all waves done with Qs before buf1 prefetch overwrites it

  f32x16 o0 = {}, o1 = {};
  float mrun = -1e30f, lrun = 0.f;

  for (int t = 0; t < 16; t++) {
    const unsigned short* const Kc = (t & 1) ? K1 : K0;
    const unsigned short* const Vc = (t & 1) ? V1 : V0;
    unsigned short* const Kn = (t & 1) ? K0 : K1;
    unsigned short* const Vn = (t & 1) ? V0 : V1;
    if (t < 15) {
      const int kv1 = (t + 1) * 64;
      const char* const vtile = vb0 + (kv1 >> 7) * 16384 + ((kv1 >> 6) & 1) * 128;
      gload16(xb_ + (size_t)(kv1 + sr) * 4608 + koff + scs, (char*)Kn + tid * 16);
      gload16(xb_ + (size_t)(kv1 + sr + 32) * 4608 + koff + scs,
              (char*)Kn + 4096 + tid * 16);
      gload16(vtile + sr * 256 + scs, (char*)Vn + tid * 16);
      gload16(vtile + (sr + 32) * 256 + scs, (char*)Vn + 4096 + tid * 16);
    }

    // swapped QK^T: S^T tiles; lane pair (l, l+32) holds q-row l&31's 64 scores
    f32x16 s0 = {}, s1 = {};
    #pragma unroll
    for (int c = 0; c < 4; c++) {
      bf16x8 kf0 = lds128(Kc, q_l, 32 * c + 16 * half);
      bf16x8 kf1 = lds128(Kc, 32 + q_l, 32 * c + 16 * half);
      s0 = __builtin_amdgcn_mfma_f32_32x32x16_bf16(kf0, qf[c], s0, 0, 0, 0);
      s1 = __builtin_amdgcn_mfma_f32_32x32x16_bf16(kf1, qf[c], s1, 0, 0, 0);
    }

    // row max: 31 in-lane + 1 permlane pair-combine
    float vmax = fmaxf(s0[0], s1[0]);
    #pragma unroll
    for (int r = 1; r < 16; r++) vmax = fmaxf(vmax, fmaxf(s0[r], s1[r]));
    {
      u32x2 mx = pswap(__float_as_uint(vmax), __float_as_uint(vmax));
      vmax = fmaxf(__uint_as_float(mx[0]), __uint_as_float(mx[1]));
    }

    // defer-max (T13): rescale only when some row grew past THR=8 (log2 units)
    if (!__all(vmax <= mrun + 8.0f)) {
      const float mnew = fmaxf(mrun, vmax);
      const float corr = __builtin_amdgcn_exp2f(mrun - mnew);
      mrun = mnew;
      lrun *= corr;
      if (lane < 32) sStat[0][wave][q_l] = corr;
      f32x4 c4[4];
      #pragma unroll
      for (int j = 0; j < 4; j++)
        c4[j] = *reinterpret_cast<const f32x4*>(&sStat[0][wave][4 * half + 8 * j]);
      #pragma unroll
      for (int r = 0; r < 16; r++) {
        const float cc = c4[r >> 2][r & 3];
        o0[r] *= cc;
        o1[r] *= cc;
      }
    }

    // P = exp2(S - m), row-sum
    float tsum = 0.f;
    #pragma unroll
    for (int r = 0; r < 16; r++) {
      const float p0 = __builtin_amdgcn_exp2f(s0[r] - mrun);
      const float p1 = __builtin_amdgcn_exp2f(s1[r] - mrun);
      s0[r] = p0; s1[r] = p1;
      tsum += p0 + p1;
    }
    {
      u32x2 ts = pswap(__float_as_uint(tsum), __float_as_uint(tsum));
      tsum = __uint_as_float(ts[0]) + __uint_as_float(ts[1]);
    }
    lrun += tsum;

    // pack P to bf16 pair-words
    unsigned pk[2][8];
    #pragma unroll
    for (int w = 0; w < 8; w++) {
      asm("v_cvt_pk_bf16_f32 %0, %1, %2"
          : "=v"(pk[0][w]) : "v"(s0[2 * w]), "v"(s0[2 * w + 1]));
      asm("v_cvt_pk_bf16_f32 %0, %1, %2"
          : "=v"(pk[1][w]) : "v"(s1[2 * w]), "v"(s1[2 * w + 1]));
    }

    // PV: per kv-chunk c, 2 permlane swaps build the A-fragment (T12)
    #pragma unroll
    for (int c = 0; c < 4; c++) {
      const int st = c >> 1, cc = c & 1;
      u32x2 rA = pswap(pk[st][4 * cc + 0], pk[st][4 * cc + 2]);
      u32x2 rB = pswap(pk[st][4 * cc + 1], pk[st][4 * cc + 3]);
      union { unsigned u[4]; bf16x8 v; } pa;
      pa.u[0] = rA[0]; pa.u[1] = rB[0]; pa.u[2] = rA[1]; pa.u[3] = rB[1];
      bf16x8 vf0 = lds128(Vc, q_l, 32 * c + 16 * half);
      bf16x8 vf1 = lds128(Vc, 32 + q_l, 32 * c + 16 * half);
      o0 = __builtin_amdgcn_mfma_f32_32x32x16_bf16(pa.v, vf0, o0, 0, 0, 0);
      o1 = __builtin_amdgcn_mfma_f32_32x32x16_bf16(pa.v, vf1, o1, 0, 0, 0);
    }
    __syncthreads();
  }

  // epilogue: 1/l per O-reg q via per-wave stat buffer (broadcast reads)
  if (lane < 32) sStat[1][wave][q_l] = lrun;
  f32x4 rl4[4];
  #pragma unroll
  for (int j = 0; j < 4; j++) {
    f32x4 lv = *reinterpret_cast<const f32x4*>(&sStat[1][wave][4 * half + 8 * j]);
    #pragma unroll
    for (int e = 0; e < 4; e++) rl4[j][e] = __builtin_amdgcn_rcpf(lv[e]);
  }
  #pragma unroll
  for (int r = 0; r < 16; r++) {
    const int qq = q0 + wave * 32 + (r & 3) + 8 * (r >> 2) + 4 * half;
    const float rl = rl4[r >> 2][r & 3];
    const size_t base = ((size_t)b * SEQ + qq) * CD + head * HD_;
    Og[base + q_l]      = f2bf(o0[r] * rl);
    Og[base + 32 + q_l] = f2bf(o1[r] * rl);
  }
}

// ---- launch -------------------------------------------------------------

extern "C" void kernel_launch(void* const* d_in, const int* in_sizes, int n_in,
                              void* d_out, int out_size, void* d_ws, size_t ws_size,
                              hipStream_t stream) {
  const float* x     = (const float*)d_in[0];
  const float* Wqkv  = (const float*)d_in[1];
  const float* Wproj = (const float*)d_in[2];
  const float* bproj = (const float*)d_in[3];

  char* ws = (char*)d_ws;
  unsigned short* qkvB = (unsigned short*)(ws + 0);          // 75,497,472
  unsigned short* Vt   = (unsigned short*)(ws + 75497472);   // 25,165,824
  unsigned short* xb   = (unsigned short*)(ws + 100663296);  // 25,165,824
  unsigned short* ao   = (unsigned short*)(ws + 100663296);  // aliases xb (xb dead)
  unsigned short* wqT  = (unsigned short*)(ws + 125829120);  //  3,538,944
  unsigned short* wpT  = (unsigned short*)(ws + 129368064);  //  1,179,648
  if (ws_size < 130547712ull) return;

  prep_kernel<<<14592, 256, 0, stream>>>(x, Wqkv, Wproj, xb, wqT, wpT);
  gemm_qkv_kernel<<<1152, 256, 0, stream>>>(xb, wqT, qkvB, Vt);
  attn_kernel<<<1536, 256, 0, stream>>>(qkvB, Vt, ao);
  gemm128_kernel<1><<<768, 256, 0, stream>>>(ao, wpT, (float*)d_out, bproj);
}

// Round 15
// 186.078 us; speedup vs baseline: 1.6348x; 1.0009x over previous
//
#include <hip/hip_runtime.h>

#define B_   16
#define NH   12
#define SEQ  1024
#define CD   768
#define HD_  64
#define MTOT (B_ * SEQ)
// 1/sqrt(64) * log2(e): QK^T scores land in log2 domain for exp2
#define QSCALE 0.18033688f

typedef __attribute__((ext_vector_type(4)))  float  f32x4;
typedef __attribute__((ext_vector_type(16))) float  f32x16;
typedef __attribute__((ext_vector_type(8)))  __bf16 bf16x8;
typedef __attribute__((ext_vector_type(2)))  unsigned u32x2;

#define WAITV12 asm volatile("s_waitcnt vmcnt(12)" ::: "memory")
#define WAITV8  asm volatile("s_waitcnt vmcnt(8)" ::: "memory")
#define WAITV6  asm volatile("s_waitcnt vmcnt(6)" ::: "memory")
#define WAITV4  asm volatile("s_waitcnt vmcnt(4)" ::: "memory")
#define WAITV0  asm volatile("s_waitcnt vmcnt(0)" ::: "memory")
#define LGKM0   asm volatile("s_waitcnt lgkmcnt(0)" ::: "memory")
#define BAR     __builtin_amdgcn_s_barrier()
#define SB0     __builtin_amdgcn_sched_barrier(0)

__device__ __forceinline__ unsigned short f2bf(float f) {
  unsigned u = __float_as_uint(f);
  u = (u + 0x7FFFu + ((u >> 16) & 1u)) >> 16;  // RNE
  return (unsigned short)u;
}

__device__ __forceinline__ void gload16(const void* g, void* l) {
  __builtin_amdgcn_global_load_lds(
      (const __attribute__((address_space(1))) void*)g,
      (__attribute__((address_space(3))) void*)l, 16, 0, 0);
}

__device__ __forceinline__ u32x2 pswap(unsigned x, unsigned y) {
  return __builtin_amdgcn_permlane32_swap(x, y, false, false);
}

// ---- merged prep: x f32->bf16 + both weight transpose-converts ----------

__global__ __launch_bounds__(256)
void prep_kernel(const float* __restrict__ x,
                 const float* __restrict__ Wqkv,
                 const float* __restrict__ Wproj,
                 unsigned short* __restrict__ xb,
                 unsigned short* __restrict__ wqT,
                 unsigned short* __restrict__ wpT) {
  __shared__ float tile[32][33];
  const int bid = blockIdx.x;
  const int tid = threadIdx.x;
  if (bid < 12288) {
    const int i = bid * 256 + tid;                 // n4 = 3145728 exact
    float4 f = reinterpret_cast<const float4*>(x)[i];
    uint2 o;
    o.x = (unsigned)f2bf(f.x) | ((unsigned)f2bf(f.y) << 16);
    o.y = (unsigned)f2bf(f.z) | ((unsigned)f2bf(f.w) << 16);
    reinterpret_cast<uint2*>(xb)[i] = o;
  } else {
    const float* W;
    unsigned short* Wt;
    int N, b2;
    if (bid < 12288 + 1728) { b2 = bid - 12288; W = Wqkv; Wt = wqT; N = 2304; }
    else                    { b2 = bid - 14016; W = Wproj; Wt = wpT; N = 768; }
    const int nb = N / 32;
    const int j0 = (b2 % nb) * 32, k0 = (b2 / nb) * 32;
    const int tx = tid & 31, ty = tid >> 5;
    #pragma unroll
    for (int i = 0; i < 4; i++)
      tile[ty + 8 * i][tx] = W[(size_t)(k0 + ty + 8 * i) * N + j0 + tx];
    __syncthreads();
    #pragma unroll
    for (int i = 0; i < 4; i++)
      Wt[(size_t)(j0 + ty + 8 * i) * 768 + k0 + tx] = f2bf(tile[tx][ty + 8 * i]);
  }
}

// ---- LDS fragment loads -------------------------------------------------

// 64B rows, swizzle ((row>>1)&3)<<4  (GEMM staging buffers)
__device__ __forceinline__ bf16x8 ldsA64(const unsigned short* buf, int row, int g) {
  int byte = (row << 6) + ((g << 4) ^ (((row >> 1) & 3) << 4));
  return *reinterpret_cast<const bf16x8*>((const char*)buf + byte);
}
// 128B rows, swizzle (row&7)<<4  (attention tiles)
__device__ __forceinline__ bf16x8 lds128(const unsigned short* buf, int row, int cb) {
  int byte = (row << 7) + (cb ^ ((row & 7) << 4));
  return *reinterpret_cast<const bf16x8*>((const char*)buf + byte);
}

// ---- QKV GEMM: 128m x 256n tile, 4 waves (each owns 128x64), ring-3 -----
// qkv[M][2304] bf16 (Q pre-scaled) + V^T blocked Vt[bh][8][64][128].
// Grid: 1152 blocks, XCD-swizzled (T1), m-major within XCD chunk so each
// XCD keeps a 16-m-tile A panel (3.1MB) L2-resident across j-panels.

__global__ __launch_bounds__(256, 2)
void gemm_qkv_kernel(const unsigned short* __restrict__ A,    // xb [16384][768]
                     const unsigned short* __restrict__ Bt,   // wqT [2304][768]
                     unsigned short* __restrict__ qkvOut,     // [16384][2304]
                     unsigned short* __restrict__ vtOut) {    // [192][8][64][128]
  constexpr int K = 768;
  // 72KB: A slots 3x8KB at u16 {0,4096,8192}; B slots 3x16KB at {12288,20480,28672}
  __shared__ unsigned short sbuf[36864];

  const int tid = threadIdx.x;
  const int lane = tid & 63;
  const int wave = tid >> 6;                      // wn: n-cols [wave*64, +64)
  // XCD swizzle: 1152 blocks, chunk 144/XCD; sw = m*9 + j (m-major in chunk)
  const int raw = blockIdx.x;
  const int sw = (raw & 7) * 144 + (raw >> 3);
  const int m0 = (sw / 9) << 7;
  const int j0 = (sw % 9) << 8;                   // 256-wide panel (section-aligned)

  const int sr = tid >> 2;                        // staging row 0..63
  const int sc = (tid & 3) << 4;
  const int scs = sc ^ (((sr >> 1) & 3) << 4);    // pre-swizzled source col

  f32x4 acc[8][4] = {};

  const char* const aSrc = (const char*)(A  + (size_t)(m0 + sr) * K) + scs;
  const char* const bSrc = (const char*)(Bt + (size_t)(j0 + sr) * K) + scs;

  auto stageT = [&](int kt, int slot) {
    const int kb = kt * 64;                       // 32 u16 along K
    char* ad = (char*)sbuf + slot * 8192 + tid * 16;
    char* bd = (char*)sbuf + 24576 + slot * 16384 + tid * 16;
    gload16(aSrc + kb, ad);                       // A rows sr, sr+64
    gload16(aSrc + kb + 98304, ad + 4096);
    #pragma unroll
    for (int p = 0; p < 4; p++)                   // B rows sr+64p
      gload16(bSrc + kb + p * 98304, bd + p * 4096);
  };

  const int g = lane >> 4;
  const int rl = lane & 15;

  auto computeT = [&](int slot) {
    const unsigned short* As = sbuf + slot * 4096;
    const unsigned short* Bs = sbuf + 12288 + slot * 8192;
    bf16x8 bf[4], af[8];
    #pragma unroll
    for (int fn = 0; fn < 4; fn++) bf[fn] = ldsA64(Bs, wave * 64 + fn * 16 + rl, g);
    #pragma unroll
    for (int fr = 0; fr < 8; fr++) af[fr] = ldsA64(As, fr * 16 + rl, g);
    #pragma unroll
    for (int fr = 0; fr < 8; fr++)
      #pragma unroll
      for (int fn = 0; fn < 4; fn++)
        acc[fr][fn] = __builtin_amdgcn_mfma_f32_16x16x32_bf16(af[fr], bf[fn],
                                                              acc[fr][fn], 0, 0, 0);
  };

  // prologue: 3 slots in flight (18 loads/thread)
  stageT(0, 0);
  stageT(1, 1);
  stageT(2, 2);

  #pragma unroll 1
  for (int t = 0; t < 21; t += 3) {
    WAITV12; BAR; SB0;
    computeT(0);
    SB0; LGKM0; BAR;
    stageT(t + 3, 0);

    WAITV12; BAR; SB0;
    computeT(1);
    SB0; LGKM0; BAR;
    stageT(t + 4, 1);

    WAITV12; BAR; SB0;
    computeT(2);
    SB0; LGKM0; BAR;
    stageT(t + 5, 2);
  }
  // tail: K-steps 21,22,23
  WAITV12; BAR; SB0;
  computeT(0);
  WAITV6; BAR; SB0;
  computeT(1);
  WAITV0; BAR; SB0;
  computeT(2);

  // ---- LDS-coalesced epilogue ----
  const int g4 = g << 2;
  BAR;                                            // all waves done with slots
  const bool secV = (j0 >= 1536);
  const float scale = (j0 < 768) ? QSCALE : 1.0f;
  char* const ct = (char*)sbuf;
  if (!secV) {
    // m-major ctile: 128 rows x 528B (256 j + 16B pad)
    #pragma unroll
    for (int fr = 0; fr < 8; fr++)
      #pragma unroll
      for (int fn = 0; fn < 4; fn++) {
        const int j_l = wave * 64 + fn * 16 + rl;
        const int mb = fr * 16 + g4;
        #pragma unroll
        for (int r = 0; r < 4; r++)
          *reinterpret_cast<unsigned short*>(ct + (mb + r) * 528 + j_l * 2) =
              f2bf(acc[fr][fn][r] * scale);
      }
  } else {
    // j-major ctile: 256 rows x 264B (128 m + 8B pad), packed 8B writes
    #pragma unroll
    for (int fr = 0; fr < 8; fr++)
      #pragma unroll
      for (int fn = 0; fn < 4; fn++) {
        const int j_l = wave * 64 + fn * 16 + rl;
        const int mb = fr * 16 + g4;
        uint2 pkd;
        pkd.x = (unsigned)f2bf(acc[fr][fn][0]) | ((unsigned)f2bf(acc[fr][fn][1]) << 16);
        pkd.y = (unsigned)f2bf(acc[fr][fn][2]) | ((unsigned)f2bf(acc[fr][fn][3]) << 16);
        *reinterpret_cast<uint2*>(ct + j_l * 264 + mb * 2) = pkd;
      }
  }
  LGKM0; BAR;
  if (!secV) {
    const int c = tid & 31, r0 = tid >> 5;        // 32 x 16B chunks per row
    char* const gb = (char*)qkvOut + (size_t)m0 * 4608 + j0 * 2 + c * 16;
    #pragma unroll
    for (int k = 0; k < 16; k++) {
      const int row = r0 + 8 * k;
      const uint4 d = *reinterpret_cast<const uint4*>(ct + row * 528 + c * 16);
      *reinterpret_cast<uint4*>(gb + (size_t)row * 4608) = d;
    }
  } else {
    const int c = tid & 15, r0 = tid >> 4;        // 16 x 16B chunks per row
    const int bidx = m0 >> 10;
    const int nblk = (m0 & 1023) >> 7;
    #pragma unroll
    for (int k = 0; k < 16; k++) {
      const int jr = r0 + 16 * k;
      const int h = ((j0 - 1536) >> 6) + (jr >> 6);
      const int d = jr & 63;
      const size_t dst = ((size_t)((bidx * NH + h) * 8 + nblk) * 64 + d) * 256 + c * 16;
      const uint4 v = *reinterpret_cast<const uint4*>(ct + jr * 264 + c * 16);
      *reinterpret_cast<uint4*>((char*)vtOut + dst) = v;
    }
  }
}

// ---- proj GEMM: 128x128 depth-3 ring, direct f32 + bias epilogue --------
// Grid 768, XCD-swizzled: chunk 96/XCD, sw = m*6 + j.

template <int MODE>
__global__ __launch_bounds__(256, 3)
void gemm128_kernel(const unsigned short* __restrict__ A,
                    const unsigned short* __restrict__ Bt,
                    float* __restrict__ outF,
                    const float* __restrict__ bias) {
  constexpr int K = 768;
  __shared__ unsigned short sbuf[24576];  // 48KB = 3 x (A 8KB + B 8KB)
  unsigned short* const A0 = sbuf;
  unsigned short* const Bb0 = sbuf + 4096;
  unsigned short* const A1 = sbuf + 8192;
  unsigned short* const Bb1 = sbuf + 12288;
  unsigned short* const A2 = sbuf + 16384;
  unsigned short* const Bb2 = sbuf + 20480;

  const int tid = threadIdx.x;
  const int lane = tid & 63;
  const int wave = tid >> 6;
  const int wm = (wave >> 1) << 6;
  const int wn = (wave & 1) << 6;
  const int raw = blockIdx.x;
  const int sw = (raw & 7) * 96 + (raw >> 3);
  const int m0 = (sw / 6) << 7;
  const int j0 = (sw % 6) << 7;

  const int sr = tid >> 2;
  const int sc = (tid & 3) << 4;
  const int scs = sc ^ (((sr >> 1) & 3) << 4);

  f32x4 acc[4][4] = {};

  const char* const ab  = (const char*)(A  + (size_t)(m0 + sr) * K) + scs;
  const char* const ab2 = (const char*)(A  + (size_t)(m0 + sr + 64) * K) + scs;
  const char* const bb  = (const char*)(Bt + (size_t)(j0 + sr) * K) + scs;
  const char* const bb2 = (const char*)(Bt + (size_t)(j0 + sr + 64) * K) + scs;

  auto stageT = [&](int kt, unsigned short* Ad, unsigned short* Bd) {
    const int kb = kt * 64;
    gload16(ab  + kb, (char*)Ad + tid * 16);
    gload16(ab2 + kb, (char*)Ad + 4096 + tid * 16);
    gload16(bb  + kb, (char*)Bd + tid * 16);
    gload16(bb2 + kb, (char*)Bd + 4096 + tid * 16);
  };

  auto computeT = [&](const unsigned short* As, const unsigned short* Bs) {
    bf16x8 af[4], bf[4];
    const int g = lane >> 4;
    #pragma unroll
    for (int fr = 0; fr < 4; fr++) af[fr] = ldsA64(As, wm + fr * 16 + (lane & 15), g);
    #pragma unroll
    for (int fn = 0; fn < 4; fn++) bf[fn] = ldsA64(Bs, wn + fn * 16 + (lane & 15), g);
    __builtin_amdgcn_s_setprio(1);
    #pragma unroll
    for (int fr = 0; fr < 4; fr++)
      #pragma unroll
      for (int fn = 0; fn < 4; fn++)
        acc[fr][fn] = __builtin_amdgcn_mfma_f32_16x16x32_bf16(af[fr], bf[fn],
                                                              acc[fr][fn], 0, 0, 0);
    __builtin_amdgcn_s_setprio(0);
  };

  stageT(0, A0, Bb0);
  stageT(1, A1, Bb1);
  stageT(2, A2, Bb2);

  #pragma unroll 1
  for (int t = 0; t < 21; t += 3) {
    WAITV8; BAR; SB0;
    computeT(A0, Bb0);
    SB0; LGKM0; BAR;
    stageT(t + 3, A0, Bb0);

    WAITV8; BAR; SB0;
    computeT(A1, Bb1);
    SB0; LGKM0; BAR;
    stageT(t + 4, A1, Bb1);

    WAITV8; BAR; SB0;
    computeT(A2, Bb2);
    SB0; LGKM0; BAR;
    stageT(t + 5, A2, Bb2);
  }
  WAITV8; BAR; SB0;
  computeT(A0, Bb0);
  WAITV4; BAR; SB0;
  computeT(A1, Bb1);
  WAITV0; BAR; SB0;
  computeT(A2, Bb2);

  const int g4 = (lane >> 4) << 2;
  #pragma unroll
  for (int fr = 0; fr < 4; fr++) {
    #pragma unroll
    for (int fn = 0; fn < 4; fn++) {
      const int jl = j0 + wn + fn * 16 + (lane & 15);
      const int mb = m0 + wm + fr * 16 + g4;
      const float bv = bias[jl];
      #pragma unroll
      for (int r = 0; r < 4; r++)
        outF[(size_t)(mb + r) * CD + jl] = acc[fr][fn][r] + bv;
    }
  }
}

// ---- flash attention: 32x32 swapped QK^T, in-lane softmax, permlane PV --
// block = (b*h, 128 q rows), 4 waves x 32 q rows each, KVBLK=64 dbuf
// Grid 1536, XCD-swizzled with q0 fast. T5: setprio around MFMA clusters
// (4 independent blocks/CU at different phases -> scheduler arbitration).

__global__ __launch_bounds__(256, 4)
void attn_kernel(const unsigned short* __restrict__ qkvB,  // [B][N][2304]
                 const unsigned short* __restrict__ Vt,    // [bh][8][64][128]
                 unsigned short* __restrict__ Og) {        // [B][1024][768] bf16
  __shared__ unsigned short ldsbuf[16384];
  __shared__ float sStat[2][4][32];  // [0]=corr, [1]=lsum

  unsigned short* const K0 = ldsbuf;
  unsigned short* const V0 = ldsbuf + 4096;
  unsigned short* const K1 = ldsbuf + 8192;
  unsigned short* const V1 = ldsbuf + 12288;
  unsigned short* const Qs = ldsbuf + 8192;  // 16KB, prologue only

  const int tid = threadIdx.x;
  const int lane = tid & 63;
  const int wave = tid >> 6;
  const int half = lane >> 5;
  const int q_l = lane & 31;
  const int raw = blockIdx.x;
  const int sw = (raw & 7) * 192 + (raw >> 3);
  const int bh = sw >> 3;
  const int q0 = (sw & 7) * 128;
  const int b = bh / NH, head = bh - b * NH;

  const int sr = tid >> 3;                       // staging row 0..31
  const int scs = ((tid & 7) << 4) ^ ((sr & 7) << 4);

  const char* const xb_ = (const char*)qkvB + (size_t)b * 1024 * 4608;
  const int qoff = head * 128;                   // byte offset within row
  const int koff = qoff + 1536;
  const char* const vb0 = (const char*)Vt + (size_t)bh * 131072;

  // prologue: Q (128 rows) + KV tile 0
  {
    #pragma unroll
    for (int i = 0; i < 4; i++)
      gload16(xb_ + (size_t)(q0 + sr + 32 * i) * 4608 + qoff + scs,
              (char*)Qs + (tid + 256 * i) * 16);
    gload16(xb_ + (size_t)sr * 4608 + koff + scs, (char*)K0 + tid * 16);
    gload16(xb_ + (size_t)(sr + 32) * 4608 + koff + scs, (char*)K0 + 4096 + tid * 16);
    gload16(vb0 + sr * 256 + scs, (char*)V0 + tid * 16);
    gload16(vb0 + (sr + 32) * 256 + scs, (char*)V0 + 4096 + tid * 16);
  }
  __syncthreads();

  bf16x8 qf[4];
  #pragma unroll
  for (int c = 0; c < 4; c++)
    qf[c] = lds128(Qs, wave * 32 + q_l, 32 * c + 16 * half);
  __syncthreads();  // all waves done with Qs before buf1 prefetch overwrites it

  f32x16 o0 = {}, o1 = {};
  float mrun = -1e30f, lrun = 0.f;

  for (int t = 0; t < 16; t++) {
    const unsigned short* const Kc = (t & 1) ? K1 : K0;
    const unsigned short* const Vc = (t & 1) ? V1 : V0;
    unsigned short* const Kn = (t & 1) ? K0 : K1;
    unsigned short* const Vn = (t & 1) ? V0 : V1;
    if (t < 15) {
      const int kv1 = (t + 1) * 64;
      const char* const vtile = vb0 + (kv1 >> 7) * 16384 + ((kv1 >> 6) & 1) * 128;
      gload16(xb_ + (size_t)(kv1 + sr) * 4608 + koff + scs, (char*)Kn + tid * 16);
      gload16(xb_ + (size_t)(kv1 + sr + 32) * 4608 + koff + scs,
              (char*)Kn + 4096 + tid * 16);
      gload16(vtile + sr * 256 + scs, (char*)Vn + tid * 16);
      gload16(vtile + (sr + 32) * 256 + scs, (char*)Vn + 4096 + tid * 16);
    }

    // swapped QK^T: S^T tiles; lane pair (l, l+32) holds q-row l&31's 64 scores
    f32x16 s0 = {}, s1 = {};
    __builtin_amdgcn_s_setprio(1);
    #pragma unroll
    for (int c = 0; c < 4; c++) {
      bf16x8 kf0 = lds128(Kc, q_l, 32 * c + 16 * half);
      bf16x8 kf1 = lds128(Kc, 32 + q_l, 32 * c + 16 * half);
      s0 = __builtin_amdgcn_mfma_f32_32x32x16_bf16(kf0, qf[c], s0, 0, 0, 0);
      s1 = __builtin_amdgcn_mfma_f32_32x32x16_bf16(kf1, qf[c], s1, 0, 0, 0);
    }
    __builtin_amdgcn_s_setprio(0);

    // row max: 31 in-lane + 1 permlane pair-combine
    float vmax = fmaxf(s0[0], s1[0]);
    #pragma unroll
    for (int r = 1; r < 16; r++) vmax = fmaxf(vmax, fmaxf(s0[r], s1[r]));
    {
      u32x2 mx = pswap(__float_as_uint(vmax), __float_as_uint(vmax));
      vmax = fmaxf(__uint_as_float(mx[0]), __uint_as_float(mx[1]));
    }

    // defer-max (T13): rescale only when some row grew past THR=8 (log2 units)
    if (!__all(vmax <= mrun + 8.0f)) {
      const float mnew = fmaxf(mrun, vmax);
      const float corr = __builtin_amdgcn_exp2f(mrun - mnew);
      mrun = mnew;
      lrun *= corr;
      if (lane < 32) sStat[0][wave][q_l] = corr;
      f32x4 c4[4];
      #pragma unroll
      for (int j = 0; j < 4; j++)
        c4[j] = *reinterpret_cast<const f32x4*>(&sStat[0][wave][4 * half + 8 * j]);
      #pragma unroll
      for (int r = 0; r < 16; r++) {
        const float cc = c4[r >> 2][r & 3];
        o0[r] *= cc;
        o1[r] *= cc;
      }
    }

    // P = exp2(S - m), row-sum
    float tsum = 0.f;
    #pragma unroll
    for (int r = 0; r < 16; r++) {
      const float p0 = __builtin_amdgcn_exp2f(s0[r] - mrun);
      const float p1 = __builtin_amdgcn_exp2f(s1[r] - mrun);
      s0[r] = p0; s1[r] = p1;
      tsum += p0 + p1;
    }
    {
      u32x2 ts = pswap(__float_as_uint(tsum), __float_as_uint(tsum));
      tsum = __uint_as_float(ts[0]) + __uint_as_float(ts[1]);
    }
    lrun += tsum;

    // pack P to bf16 pair-words
    unsigned pk[2][8];
    #pragma unroll
    for (int w = 0; w < 8; w++) {
      asm("v_cvt_pk_bf16_f32 %0, %1, %2"
          : "=v"(pk[0][w]) : "v"(s0[2 * w]), "v"(s0[2 * w + 1]));
      asm("v_cvt_pk_bf16_f32 %0, %1, %2"
          : "=v"(pk[1][w]) : "v"(s1[2 * w]), "v"(s1[2 * w + 1]));
    }

    // PV: per kv-chunk c, 2 permlane swaps build the A-fragment (T12)
    __builtin_amdgcn_s_setprio(1);
    #pragma unroll
    for (int c = 0; c < 4; c++) {
      const int st = c >> 1, cc = c & 1;
      u32x2 rA = pswap(pk[st][4 * cc + 0], pk[st][4 * cc + 2]);
      u32x2 rB = pswap(pk[st][4 * cc + 1], pk[st][4 * cc + 3]);
      union { unsigned u[4]; bf16x8 v; } pa;
      pa.u[0] = rA[0]; pa.u[1] = rB[0]; pa.u[2] = rA[1]; pa.u[3] = rB[1];
      bf16x8 vf0 = lds128(Vc, q_l, 32 * c + 16 * half);
      bf16x8 vf1 = lds128(Vc, 32 + q_l, 32 * c + 16 * half);
      o0 = __builtin_amdgcn_mfma_f32_32x32x16_bf16(pa.v, vf0, o0, 0, 0, 0);
      o1 = __builtin_amdgcn_mfma_f32_32x32x16_bf16(pa.v, vf1, o1, 0, 0, 0);
    }
    __builtin_amdgcn_s_setprio(0);
    __syncthreads();
  }

  // epilogue: 1/l per O-reg q via per-wave stat buffer (broadcast reads)
  if (lane < 32) sStat[1][wave][q_l] = lrun;
  f32x4 rl4[4];
  #pragma unroll
  for (int j = 0; j < 4; j++) {
    f32x4 lv = *reinterpret_cast<const f32x4*>(&sStat[1][wave][4 * half + 8 * j]);
    #pragma unroll
    for (int e = 0; e < 4; e++) rl4[j][e] = __builtin_amdgcn_rcpf(lv[e]);
  }
  #pragma unroll
  for (int r = 0; r < 16; r++) {
    const int qq = q0 + wave * 32 + (r & 3) + 8 * (r >> 2) + 4 * half;
    const float rl = rl4[r >> 2][r & 3];
    const size_t base = ((size_t)b * SEQ + qq) * CD + head * HD_;
    Og[base + q_l]      = f2bf(o0[r] * rl);
    Og[base + 32 + q_l] = f2bf(o1[r] * rl);
  }
}

// ---- launch -------------------------------------------------------------

extern "C" void kernel_launch(void* const* d_in, const int* in_sizes, int n_in,
                              void* d_out, int out_size, void* d_ws, size_t ws_size,
                              hipStream_t stream) {
  const float* x     = (const float*)d_in[0];
  const float* Wqkv  = (const float*)d_in[1];
  const float* Wproj = (const float*)d_in[2];
  const float* bproj = (const float*)d_in[3];

  char* ws = (char*)d_ws;
  unsigned short* qkvB = (unsigned short*)(ws + 0);          // 75,497,472
  unsigned short* Vt   = (unsigned short*)(ws + 75497472);   // 25,165,824
  unsigned short* xb   = (unsigned short*)(ws + 100663296);  // 25,165,824
  unsigned short* ao   = (unsigned short*)(ws + 100663296);  // aliases xb (xb dead)
  unsigned short* wqT  = (unsigned short*)(ws + 125829120);  //  3,538,944
  unsigned short* wpT  = (unsigned short*)(ws + 129368064);  //  1,179,648
  if (ws_size < 130547712ull) return;

  prep_kernel<<<14592, 256, 0, stream>>>(x, Wqkv, Wproj, xb, wqT, wpT);
  gemm_qkv_kernel<<<1152, 256, 0, stream>>>(xb, wqT, qkvB, Vt);
  attn_kernel<<<1536, 256, 0, stream>>>(qkvB, Vt, ao);
  gemm128_kernel<1><<<768, 256, 0, stream>>>(ao, wpT, (float*)d_out, bproj);
}